// Round 1
// 638.320 us; speedup vs baseline: 1.6544x; 1.6544x over previous
//
#include <hip/hip_runtime.h>
#include <hip/hip_bf16.h>
#include <math.h>

#define NN 4096
#define NE 1024
#define DIN 256
#define HD 64

typedef __hip_bfloat16 bf16;
__device__ __forceinline__ float b2f(bf16 x){ return __bfloat162float(x); }

typedef __attribute__((ext_vector_type(8))) short s16x8;   // 8 bf16 = 4 VGPR
typedef __attribute__((ext_vector_type(4))) float f32x4;   // MFMA 16x16 acc

// ---- 1. adj column sums (atomic partials over row chunks) ----
__global__ void k_colsum(const float* __restrict__ adj, float* __restrict__ colsum){
  int e  = blockIdx.x*256 + threadIdx.x;
  int i0 = blockIdx.y*128;
  float acc = 0.f;
  for (int i = 0; i < 128; ++i)
    acc += adj[(size_t)(i0+i)*NE + e];
  atomicAdd(&colsum[e], acc);
}

// ---- 2. ecT_raw[e][c] += (feats^T @ adj)[c][e] over K chunk. ----
__global__ void k_ect(const float* __restrict__ feats, const float* __restrict__ adj,
                      float* __restrict__ ecT){
  __shared__ float As[64][65]; // [k(i)][m(c)]
  __shared__ float Bs[64][65]; // [k(i)][n(e)]
  int c0 = blockIdx.x*64, e0 = blockIdx.y*64;
  int kb = blockIdx.z*256;
  int tid = threadIdx.x, tx = tid & 15, ty = tid >> 4;
  float acc[4][4] = {};
  for (int k0 = kb; k0 < kb+256; k0 += 64){
    for (int idx = tid; idx < 4096; idx += 256){
      int r = idx >> 6, c = idx & 63;
      As[r][c] = feats[(size_t)(k0+r)*DIN + c0 + c];
      Bs[r][c] = adj  [(size_t)(k0+r)*NE  + e0 + c];
    }
    __syncthreads();
    for (int k = 0; k < 64; ++k){
      float a[4], b[4];
      #pragma unroll
      for (int i=0;i<4;++i) a[i] = As[k][tx*4+i];
      #pragma unroll
      for (int i=0;i<4;++i) b[i] = Bs[k][ty*4+i];
      #pragma unroll
      for (int mi=0;mi<4;++mi)
        #pragma unroll
        for (int ni=0;ni<4;++ni) acc[mi][ni] += a[mi]*b[ni];
    }
    __syncthreads();
  }
  for (int mi=0;mi<4;++mi)
    for (int ni=0;ni<4;++ni){
      int cc = c0 + tx*4 + mi, ee = e0 + ty*4 + ni;
      atomicAdd(&ecT[(size_t)ee*DIN + cc], acc[mi][ni]);
    }
}

// ---- 3. s = LN1((ecT/colsum) @ lin_w^T); sw = s*w_o, sq_s = sum_h w*s^2 ----
__global__ void k_s(const float* __restrict__ ecT, const float* __restrict__ colsum,
                    const float* __restrict__ lin_w,
                    const float* __restrict__ ln1w, const float* __restrict__ ln1b,
                    const float* __restrict__ wow,
                    float* __restrict__ sw, float* __restrict__ sq_s){
  int e = blockIdx.x, h = threadIdx.x;
  const float* row = ecT + (size_t)e*DIN;
  const float* lw  = lin_w + (size_t)h*DIN;
  float acc = 0.f;
  for (int c = 0; c < DIN; ++c) acc += row[c]*lw[c];
  acc /= colsum[e];                 // exact: dot is linear in the ecT row
  float tot = acc;
  for (int m=32;m>=1;m>>=1) tot += __shfl_xor(tot,m);
  float mean = tot*(1.f/64.f);
  float dv = acc - mean;
  float vv = dv*dv;
  for (int m=32;m>=1;m>>=1) vv += __shfl_xor(vv,m);
  float y = dv*(1.f/sqrtf(vv*(1.f/64.f)+1e-5f))*ln1w[h] + ln1b[h];
  float wv = wow[h];
  sw[(size_t)e*HD + h] = y*wv;
  float q = wv*y*y;
  for (int m=32;m>=1;m>>=1) q += __shfl_xor(q,m);
  if (h==0) sq_s[e] = q;
}

// ---- 4. f += feats @ W_v^T over K chunk ----
__global__ void k_f(const float* __restrict__ feats, const float* __restrict__ Wv,
                    float* __restrict__ f){
  __shared__ float As[64][65]; // [k(c)][m(i)]
  __shared__ float Bs[64][65]; // [k(c)][n(h)]
  int i0 = blockIdx.x*64;
  int c0 = blockIdx.y*64;
  int tid=threadIdx.x, tx=tid&15, ty=tid>>4;
  float acc[4][4]={};
  for (int idx=tid; idx<4096; idx+=256){
    int r=idx>>6, c=idx&63;
    As[c][r] = feats[(size_t)(i0+r)*DIN + c0+c];
    Bs[c][r] = Wv   [(size_t)r*DIN      + c0+c];
  }
  __syncthreads();
  for (int k=0;k<64;++k){
    float a[4], b[4];
    #pragma unroll
    for (int i=0;i<4;++i) a[i] = As[k][tx*4+i];
    #pragma unroll
    for (int i=0;i<4;++i) b[i] = Bs[k][ty*4+i];
    #pragma unroll
    for (int mi=0;mi<4;++mi)
      #pragma unroll
      for (int ni=0;ni<4;++ni) acc[mi][ni] += a[mi]*b[ni];
  }
  for (int mi=0;mi<4;++mi)
    for (int ni=0;ni<4;++ni)
      atomicAdd(&f[(size_t)(i0+tx*4+mi)*HD + ty*4+ni], acc[mi][ni]);
}

// ---- 5. rowsum[i] = sum_j exp(f_i . f_j / 8) ----
__global__ void k_rowsum(const float* __restrict__ f, float* __restrict__ rowsum){
  __shared__ float Fi[64][65];  // [h][i_local]
  __shared__ float Fj[64][65];  // [h][j_local]
  __shared__ float red[64][17];
  int i0 = blockIdx.x*64;
  int tid=threadIdx.x, tx=tid&15, ty=tid>>4;
  for (int idx=tid; idx<4096; idx+=256){
    int r=idx>>6, c=idx&63;
    Fi[c][r] = f[(size_t)(i0+r)*HD + c];
  }
  float psum[4] = {0.f,0.f,0.f,0.f};
  for (int jt=0; jt<8; ++jt){
    int j0 = blockIdx.y*512 + jt*64;
    __syncthreads();
    for (int idx=tid; idx<4096; idx+=256){
      int r=idx>>6, c=idx&63;
      Fj[c][r] = f[(size_t)(j0+r)*HD + c];
    }
    __syncthreads();
    float acc[4][4]={};
    for (int k=0;k<64;++k){
      float a[4], b[4];
      #pragma unroll
      for (int i=0;i<4;++i) a[i] = Fi[k][tx*4+i];
      #pragma unroll
      for (int i=0;i<4;++i) b[i] = Fj[k][ty*4+i];
      #pragma unroll
      for (int mi=0;mi<4;++mi)
        #pragma unroll
        for (int ni=0;ni<4;++ni) acc[mi][ni] += a[mi]*b[ni];
    }
    #pragma unroll
    for (int mi=0;mi<4;++mi)
      #pragma unroll
      for (int ni=0;ni<4;++ni) psum[mi] += __expf(acc[mi][ni]*0.125f);
  }
  __syncthreads();
  for (int mi=0;mi<4;++mi) red[tx*4+mi][ty] = psum[mi];
  __syncthreads();
  if (tid < 64){
    float s = 0.f;
    for (int t=0;t<16;++t) s += red[tid][t];
    atomicAdd(&rowsum[i0+tid], s);
  }
}

// ---- 6. dpre_unnorm += exp(S_tile) @ f_tile ----
__global__ void k_av(const float* __restrict__ f, float* __restrict__ dpre){
  __shared__ float Fi [64][65]; // [h][i]
  __shared__ float FjT[64][65]; // [h][j] for scores; then P[j][i]
  __shared__ float Fj [64][65]; // [j][h] for PV
  int i0 = blockIdx.x*64;
  int tid=threadIdx.x, tx=tid&15, ty=tid>>4;
  for (int idx=tid; idx<4096; idx+=256){
    int r=idx>>6, c=idx&63;
    Fi[c][r] = f[(size_t)(i0+r)*HD + c];
  }
  float acco[4][4]={};  // [mi(i)][hi(h)]
  for (int jt=0; jt<16; ++jt){
    int j0 = blockIdx.y*1024 + jt*64;
    __syncthreads();
    for (int idx=tid; idx<4096; idx+=256){
      int r=idx>>6, c=idx&63;
      float v = f[(size_t)(j0+r)*HD + c];
      FjT[c][r] = v;
      Fj [r][c] = v;
    }
    __syncthreads();
    float accs[4][4]={};   // [mi(i)][ni(j)]
    for (int k=0;k<64;++k){
      float a[4], b[4];
      #pragma unroll
      for (int i=0;i<4;++i) a[i] = Fi [k][tx*4+i];
      #pragma unroll
      for (int i=0;i<4;++i) b[i] = FjT[k][ty*4+i];
      #pragma unroll
      for (int mi=0;mi<4;++mi)
        #pragma unroll
        for (int ni=0;ni<4;++ni) accs[mi][ni] += a[mi]*b[ni];
    }
    __syncthreads();
    #pragma unroll
    for (int mi=0;mi<4;++mi)
      #pragma unroll
      for (int ni=0;ni<4;++ni)
        FjT[ty*4+ni][tx*4+mi] = __expf(accs[mi][ni]*0.125f);  // P[j][i]
    __syncthreads();
    for (int k=0;k<64;++k){
      float p[4], b[4];
      #pragma unroll
      for (int i=0;i<4;++i) p[i] = FjT[k][tx*4+i];   // P[j=k][i]
      #pragma unroll
      for (int i=0;i<4;++i) b[i] = Fj [k][ty*4+i];   // f[j=k][h]
      #pragma unroll
      for (int mi=0;mi<4;++mi)
        #pragma unroll
        for (int hi=0;hi<4;++hi) acco[mi][hi] += p[mi]*b[hi];
    }
  }
  for (int mi=0;mi<4;++mi)
    for (int hi=0;hi<4;++hi)
      atomicAdd(&dpre[(size_t)(i0+tx*4+mi)*HD + ty*4+hi], acco[mi][hi]);
}

// ---- 7. d = LN2(dpre/rowsum); dmat, sq_d ----
__global__ void k_dln(const float* __restrict__ dpre, const float* __restrict__ rowsum,
                      const float* __restrict__ ln2w, const float* __restrict__ ln2b,
                      const float* __restrict__ wow,
                      float* __restrict__ dmat, float* __restrict__ sq_d){
  int lane = threadIdx.x & 63;
  int n = blockIdx.x*4 + (threadIdx.x>>6);
  float x = dpre[(size_t)n*HD + lane] / rowsum[n];
  float tot = x;
  for (int m=32;m>=1;m>>=1) tot += __shfl_xor(tot,m);
  float mean = tot*(1.f/64.f);
  float dv = x - mean;
  float vv = dv*dv;
  for (int m=32;m>=1;m>>=1) vv += __shfl_xor(vv,m);
  float y = dv*(1.f/sqrtf(vv*(1.f/64.f)+1e-5f))*ln2w[lane] + ln2b[lane];
  dmat[(size_t)n*HD + lane] = y;
  float wv = wow[lane];
  float q = wv*y*y;
  for (int m=32;m>=1;m>>=1) q += __shfl_xor(q,m);
  if (lane==0) sq_d[n] = q;
}

// ---- 8. Hm[n][e] = exp(-(sq_s[e]+sq_d[n]-2*dot(sw[e],d[n])+b)/800), store bf16 ----
__global__ void k_hm(const float* __restrict__ dmat, const float* __restrict__ sw,
                     const float* __restrict__ sq_d, const float* __restrict__ sq_s,
                     const float* __restrict__ wob, bf16* __restrict__ Hm){
  __shared__ float As[64][65]; // [k(h)][m(n)]
  __shared__ float Bs[64][65]; // [k(h)][n(e)]
  int n0 = blockIdx.x*64, e0 = blockIdx.y*64;
  int tid=threadIdx.x, tx=tid&15, ty=tid>>4;
  for (int idx=tid; idx<4096; idx+=256){
    int r=idx>>6, c=idx&63;
    As[c][r] = dmat[(size_t)(n0+r)*HD + c];
    Bs[c][r] = sw  [(size_t)(e0+r)*HD + c];
  }
  __syncthreads();
  float acc[4][4]={};
  for (int k=0;k<64;++k){
    float a[4], b[4];
    #pragma unroll
    for (int i=0;i<4;++i) a[i] = As[k][tx*4+i];
    #pragma unroll
    for (int i=0;i<4;++i) b[i] = Bs[k][ty*4+i];
    #pragma unroll
    for (int mi=0;mi<4;++mi)
      #pragma unroll
      for (int ni=0;ni<4;++ni) acc[mi][ni] += a[mi]*b[ni];
  }
  float bias = wob[0];
  for (int mi=0;mi<4;++mi)
    for (int ni=0;ni<4;++ni){
      int nn = n0+tx*4+mi, ee = e0+ty*4+ni;
      float ta = sq_s[ee] + sq_d[nn] - 2.f*acc[mi][ni] + bias;
      float arg = -ta*(1.f/800.f);
      if (!(arg > -88.f)) arg = -88.f;
      if (arg > 60.f)     arg = 60.f;
      Hm[(size_t)nn*NE + ee] = __float2bfloat16(__expf(arg));
    }
}

// ---- 9. invDV[n] = (row sum of Hm)^-0.5 ----
__global__ void k_dv(const bf16* __restrict__ Hm, float* __restrict__ invDV){
  __shared__ float sm[256];
  int n = blockIdx.x, t = threadIdx.x;
  const bf16* row = Hm + (size_t)n*NE;
  float a = b2f(row[t]) + b2f(row[t+256]) + b2f(row[t+512]) + b2f(row[t+768]);
  sm[t]=a; __syncthreads();
  for (int s=128;s>0;s>>=1){ if(t<s) sm[t]+=sm[t+s]; __syncthreads(); }
  if (t==0){ float v = sm[0]; invDV[n] = (v>0.f) ? 1.f/sqrtf(v) : 0.f; }
}

// ---- 10. DE col sums -> rsqrt(DE)  (sqrt of invDE; folded into BOTH GEMM sides) ----
__global__ void k_de(const bf16* __restrict__ Hm, float* __restrict__ DE){
  int e  = blockIdx.x*256 + threadIdx.x;
  int i0 = blockIdx.y*128;
  float acc=0.f;
  for (int i=0;i<128;++i) acc += b2f(Hm[(size_t)(i0+i)*NE + e]);
  atomicAdd(&DE[e], acc);
}
__global__ void k_invde(float* __restrict__ DE){
  int e = blockIdx.x*256 + threadIdx.x;
  float v = DE[e];
  DE[e] = (v>0.f) ? rsqrtf(v) : 0.f;   // sqrt(1/DE): A2@A2^T then gives Hm*invDE*Hm^T
}

// ---- 10b. In-place: A2[n][e] = Hm[n][e] * rsqrt(DE[e])  (bf16, vectorized x8) ----
__global__ void k_scale(bf16* __restrict__ Hm, const float* __restrict__ rde){
  int idx = blockIdx.x*256 + threadIdx.x;  // one 8-elem group per thread
  int row = idx >> 7, c8 = idx & 127;
  size_t base = (size_t)row*NE + c8*8;
  s16x8 v = *(const s16x8*)(Hm + base);
  s16x8 o;
  #pragma unroll
  for (int j = 0; j < 8; ++j){
    unsigned int w = ((unsigned int)(unsigned short)v[j]) << 16;
    float fv; __builtin_memcpy(&fv, &w, 4);
    fv *= rde[c8*8 + j];
    unsigned int u; __builtin_memcpy(&u, &fv, 4);
    u += 0x7fff + ((u >> 16) & 1);           // RNE to bf16 (values finite, >=0)
    o[j] = (short)(u >> 16);
  }
  *(s16x8*)(Hm + base) = o;
}

// ---- 11. out = 0.99*G + 0.01*invDV_i*invDV_j*(A2 @ A2^T)  -- bf16 MFMA GEMM.
//      m97 structure: 128x128 tile, 4 waves (2x2), 4x4 frags of 16x16x32,
//      BK=64, global_load_lds w=16 with pre-swizzled source (seg ^= row&7)
//      + swizzled ds_read_b128 (rows are 128 B -> unswizzled = 16-way conflict).
//      Upper-tri blocks only; mirror via LDS in 2 phases (LDS reused, 33.3 KB). ----
__global__ void __launch_bounds__(256)
k_final(const bf16* __restrict__ A2, const float* __restrict__ invDV,
        const float* __restrict__ G, float* __restrict__ out){
  int bi = blockIdx.x, bj = blockIdx.y;
  if (bj < bi) return;
  __shared__ __align__(16) unsigned char smraw[2*64*65*4];   // 33280 B; stage uses 32768
  const int t    = threadIdx.x;
  const int lane = t & 63;
  const int w    = t >> 6;
  const int wr   = w >> 1, wc = w & 1;     // wave -> 64x64 quadrant
  const int i0 = bi*128, j0 = bj*128;
  const int seg   = t & 7;
  const int rbase = t >> 3;                // 0..31

  f32x4 acc[4][4] = {};

  for (int k0 = 0; k0 < NE; k0 += 64){
    // stage A rows [i0..i0+127], B rows [j0..j0+127], 64 K-cols, linear LDS dest,
    // inverse-swizzled global source so swizzled reads find their data
    #pragma unroll
    for (int it = 0; it < 4; ++it){
      int r  = it*32 + rbase;
      int ss = seg ^ (r & 7);
      const bf16* ga = A2 + (size_t)(i0 + r)*NE + k0 + ss*8;
      const bf16* gb = A2 + (size_t)(j0 + r)*NE + k0 + ss*8;
      __builtin_amdgcn_global_load_lds(
        (const __attribute__((address_space(1))) void*)ga,
        (__attribute__((address_space(3))) void*)(smraw + it*4096 + t*16), 16, 0, 0);
      __builtin_amdgcn_global_load_lds(
        (const __attribute__((address_space(1))) void*)gb,
        (__attribute__((address_space(3))) void*)(smraw + 16384 + it*4096 + t*16), 16, 0, 0);
    }
    __syncthreads();   // drains vmcnt(0)
    #pragma unroll
    for (int kk = 0; kk < 2; ++kk){
      s16x8 a[4], b[4];
      #pragma unroll
      for (int mi = 0; mi < 4; ++mi){
        int row = wr*64 + mi*16 + (lane & 15);
        int s   = kk*4 + (lane >> 4);
        a[mi] = *(const s16x8*)(smraw + row*128 + ((s ^ (row & 7))*16));
      }
      #pragma unroll
      for (int ni = 0; ni < 4; ++ni){
        int row = wc*64 + ni*16 + (lane & 15);
        int s   = kk*4 + (lane >> 4);
        b[ni] = *(const s16x8*)(smraw + 16384 + row*128 + ((s ^ (row & 7))*16));
      }
      #pragma unroll
      for (int mi = 0; mi < 4; ++mi)
        #pragma unroll
        for (int ni = 0; ni < 4; ++ni)
          acc[mi][ni] = __builtin_amdgcn_mfma_f32_16x16x32_bf16(a[mi], b[ni], acc[mi][ni], 0, 0, 0);
    }
    __syncthreads();
  }

  // epilogue: C/D frag map (m89-verified): col = lane&15, row = (lane>>4)*4 + reg
  float dvi[4][4], dvj[4];
  #pragma unroll
  for (int mi = 0; mi < 4; ++mi)
    #pragma unroll
    for (int q = 0; q < 4; ++q)
      dvi[mi][q] = invDV[i0 + wr*64 + mi*16 + (lane>>4)*4 + q];
  #pragma unroll
  for (int ni = 0; ni < 4; ++ni)
    dvj[ni] = invDV[j0 + wc*64 + ni*16 + (lane & 15)];

  #pragma unroll
  for (int mi = 0; mi < 4; ++mi)
    #pragma unroll
    for (int q = 0; q < 4; ++q){
      int ii = i0 + wr*64 + mi*16 + (lane>>4)*4 + q;
      #pragma unroll
      for (int ni = 0; ni < 4; ++ni){
        int jj = j0 + wc*64 + ni*16 + (lane & 15);
        size_t o = (size_t)ii*NN + jj;
        out[o] = 0.99f*G[o] + 0.01f*(dvi[mi][q]*dvj[ni]*acc[mi][ni][q]);
      }
    }

  if (bi == bj) return;
  // mirror lower-triangle tile via LDS (2 wave-rows at a time; 2x 64x65 f32 buffers)
  float (*Mir)[64][65] = (float(*)[64][65])smraw;
  for (int p = 0; p < 2; ++p){
    if (wr == p){
      #pragma unroll
      for (int mi = 0; mi < 4; ++mi)
        #pragma unroll
        for (int ni = 0; ni < 4; ++ni)
          #pragma unroll
          for (int q = 0; q < 4; ++q)
            Mir[wc][ni*16 + (lane & 15)][mi*16 + (lane>>4)*4 + q] =
              0.01f*(dvi[mi][q]*dvj[ni]*acc[mi][ni][q]);
    }
    __syncthreads();
    #pragma unroll
    for (int b = 0; b < 2; ++b){
      for (int itr = 0; itr < 16; ++itr){
        int idx = itr*256 + t;
        int jl = idx >> 6, il = idx & 63;
        size_t o = (size_t)(j0 + b*64 + jl)*NN + (i0 + p*64 + il);
        out[o] = 0.99f*G[o] + Mir[b][jl][il];
      }
    }
    __syncthreads();
  }
}

extern "C" void kernel_launch(void* const* d_in, const int* in_sizes, int n_in,
                              void* d_out, int out_size, void* d_ws, size_t ws_size,
                              hipStream_t stream){
  const float* adj  = (const float*)d_in[0];
  const float* G    = (const float*)d_in[1];
  const float* feats= (const float*)d_in[2];
  const float* Wv   = (const float*)d_in[3];
  const float* lin  = (const float*)d_in[4];
  const float* wow  = (const float*)d_in[5];
  const float* wob  = (const float*)d_in[6];
  const float* ln1w = (const float*)d_in[7];
  const float* ln1b = (const float*)d_in[8];
  const float* ln2w = (const float*)d_in[9];
  const float* ln2b = (const float*)d_in[10];
  float* out = (float*)d_out;

  float* w = (float*)d_ws;
  float* colsum = w; w += NE;
  float* DE     = w; w += NE;   // becomes rsqrt(DE) in place
  float* sq_s   = w; w += NE;
  float* rowsum = w; w += NN;
  float* sq_d   = w; w += NN;
  float* invDV  = w; w += NN;
  float* ecT    = w; w += NE*DIN;
  float* swp    = w; w += NE*HD;
  float* f      = w; w += NN*HD;
  float* dpre   = w; w += NN*HD;
  float* dmat   = w; w += NN*HD;
  bf16*  Hm     = (bf16*)w;     // NN*NE bf16 = 8 MB; scaled in place to A2 after k_dv/k_de

  hipMemsetAsync(colsum, 0, NE*sizeof(float), stream);
  hipMemsetAsync(DE,     0, NE*sizeof(float), stream);
  hipMemsetAsync(rowsum, 0, NN*sizeof(float), stream);
  hipMemsetAsync(ecT,    0, (size_t)NE*DIN*sizeof(float), stream);
  hipMemsetAsync(f,      0, (size_t)NN*HD*sizeof(float), stream);
  hipMemsetAsync(dpre,   0, (size_t)NN*HD*sizeof(float), stream);

  k_colsum <<<dim3(4,32),    256, 0, stream>>>(adj, colsum);
  k_ect    <<<dim3(4,16,16), 256, 0, stream>>>(feats, adj, ecT);
  k_s      <<<NE,             64, 0, stream>>>(ecT, colsum, lin, ln1w, ln1b, wow, swp, sq_s);
  k_f      <<<dim3(64,4),    256, 0, stream>>>(feats, Wv, f);
  k_rowsum <<<dim3(64,8),    256, 0, stream>>>(f, rowsum);
  k_av     <<<dim3(64,4),    256, 0, stream>>>(f, dpre);
  k_dln    <<<NN/4,          256, 0, stream>>>(dpre, rowsum, ln2w, ln2b, wow, dmat, sq_d);
  k_hm     <<<dim3(64,16),   256, 0, stream>>>(dmat, swp, sq_d, sq_s, wob, Hm);
  k_dv     <<<NN,            256, 0, stream>>>(Hm, invDV);
  k_de     <<<dim3(4,32),    256, 0, stream>>>(Hm, DE);
  k_invde  <<<4,             256, 0, stream>>>(DE);
  k_scale  <<<2048,          256, 0, stream>>>(Hm, DE);
  k_final  <<<dim3(32,32),   256, 0, stream>>>(Hm, invDV, G, out);
}

// Round 2
// 438.699 us; speedup vs baseline: 2.4072x; 1.4550x over previous
//
#include <hip/hip_runtime.h>
#include <hip/hip_bf16.h>
#include <math.h>

#define NN 4096
#define NE 1024
#define DIN 256
#define HD 64

typedef __hip_bfloat16 bf16;
__device__ __forceinline__ float b2f(bf16 x){ return __bfloat162float(x); }

typedef __attribute__((ext_vector_type(8))) short s16x8;   // 8 bf16 = 4 VGPR
typedef __attribute__((ext_vector_type(4))) float f32x4;   // MFMA 16x16 acc

__device__ __forceinline__ unsigned short f2b_rne(float x){  // RNE f32->bf16 (finite)
  unsigned u; __builtin_memcpy(&u, &x, 4);
  u += 0x7fff + ((u>>16)&1);
  return (unsigned short)(u>>16);
}

// ---- 1. adj column sums (atomic partials over row chunks) ----
__global__ void k_colsum(const float* __restrict__ adj, float* __restrict__ colsum){
  int e  = blockIdx.x*256 + threadIdx.x;
  int i0 = blockIdx.y*128;
  float acc = 0.f;
  for (int i = 0; i < 128; ++i)
    acc += adj[(size_t)(i0+i)*NE + e];
  atomicAdd(&colsum[e], acc);
}

// ---- 2. ecT_raw[e][c] += (feats^T @ adj)[c][e] over K chunk. ----
__global__ void k_ect(const float* __restrict__ feats, const float* __restrict__ adj,
                      float* __restrict__ ecT){
  __shared__ float As[64][65]; // [k(i)][m(c)]
  __shared__ float Bs[64][65]; // [k(i)][n(e)]
  int c0 = blockIdx.x*64, e0 = blockIdx.y*64;
  int kb = blockIdx.z*256;
  int tid = threadIdx.x, tx = tid & 15, ty = tid >> 4;
  float acc[4][4] = {};
  for (int k0 = kb; k0 < kb+256; k0 += 64){
    for (int idx = tid; idx < 4096; idx += 256){
      int r = idx >> 6, c = idx & 63;
      As[r][c] = feats[(size_t)(k0+r)*DIN + c0 + c];
      Bs[r][c] = adj  [(size_t)(k0+r)*NE  + e0 + c];
    }
    __syncthreads();
    for (int k = 0; k < 64; ++k){
      float a[4], b[4];
      #pragma unroll
      for (int i=0;i<4;++i) a[i] = As[k][tx*4+i];
      #pragma unroll
      for (int i=0;i<4;++i) b[i] = Bs[k][ty*4+i];
      #pragma unroll
      for (int mi=0;mi<4;++mi)
        #pragma unroll
        for (int ni=0;ni<4;++ni) acc[mi][ni] += a[mi]*b[ni];
    }
    __syncthreads();
  }
  for (int mi=0;mi<4;++mi)
    for (int ni=0;ni<4;++ni){
      int cc = c0 + tx*4 + mi, ee = e0 + ty*4 + ni;
      atomicAdd(&ecT[(size_t)ee*DIN + cc], acc[mi][ni]);
    }
}

// ---- 3. s = LN1((ecT/colsum) @ lin_w^T); sw = s*w_o, sq_s = sum_h w*s^2 ----
__global__ void k_s(const float* __restrict__ ecT, const float* __restrict__ colsum,
                    const float* __restrict__ lin_w,
                    const float* __restrict__ ln1w, const float* __restrict__ ln1b,
                    const float* __restrict__ wow,
                    float* __restrict__ sw, float* __restrict__ sq_s){
  int e = blockIdx.x, h = threadIdx.x;
  const float* row = ecT + (size_t)e*DIN;
  const float* lw  = lin_w + (size_t)h*DIN;
  float acc = 0.f;
  for (int c = 0; c < DIN; ++c) acc += row[c]*lw[c];
  acc /= colsum[e];                 // exact: dot is linear in the ecT row
  float tot = acc;
  for (int m=32;m>=1;m>>=1) tot += __shfl_xor(tot,m);
  float mean = tot*(1.f/64.f);
  float dv = acc - mean;
  float vv = dv*dv;
  for (int m=32;m>=1;m>>=1) vv += __shfl_xor(vv,m);
  float y = dv*(1.f/sqrtf(vv*(1.f/64.f)+1e-5f))*ln1w[h] + ln1b[h];
  float wv = wow[h];
  sw[(size_t)e*HD + h] = y*wv;
  float q = wv*y*y;
  for (int m=32;m>=1;m>>=1) q += __shfl_xor(q,m);
  if (h==0) sq_s[e] = q;
}

// ---- 4. f += feats @ W_v^T over K chunk ----
__global__ void k_f(const float* __restrict__ feats, const float* __restrict__ Wv,
                    float* __restrict__ f){
  __shared__ float As[64][65]; // [k(c)][m(i)]
  __shared__ float Bs[64][65]; // [k(c)][n(h)]
  int i0 = blockIdx.x*64;
  int c0 = blockIdx.y*64;
  int tid=threadIdx.x, tx=tid&15, ty=tid>>4;
  float acc[4][4]={};
  for (int idx=tid; idx<4096; idx+=256){
    int r=idx>>6, c=idx&63;
    As[c][r] = feats[(size_t)(i0+r)*DIN + c0+c];
    Bs[c][r] = Wv   [(size_t)r*DIN      + c0+c];
  }
  __syncthreads();
  for (int k=0;k<64;++k){
    float a[4], b[4];
    #pragma unroll
    for (int i=0;i<4;++i) a[i] = As[k][tx*4+i];
    #pragma unroll
    for (int i=0;i<4;++i) b[i] = Bs[k][ty*4+i];
    #pragma unroll
    for (int mi=0;mi<4;++mi)
      #pragma unroll
      for (int ni=0;ni<4;++ni) acc[mi][ni] += a[mi]*b[ni];
  }
  for (int mi=0;mi<4;++mi)
    for (int ni=0;ni<4;++ni)
      atomicAdd(&f[(size_t)(i0+tx*4+mi)*HD + ty*4+ni], acc[mi][ni]);
}

// ---- 4b. fb = bf16(f), fbT = bf16(f)^T (64x4096, h-major) for the MFMA attn ----
__global__ void k_f2b(const float* __restrict__ f, unsigned short* __restrict__ fb,
                      unsigned short* __restrict__ fbT){
  __shared__ unsigned short Ls[64][72];
  int n0 = blockIdx.x*64;
  int t = threadIdx.x;
  int r = t>>2, c0 = (t&3)*16;
  unsigned short tmp[16];
  #pragma unroll
  for (int s=0;s<16;++s) tmp[s] = f2b_rne(f[(size_t)(n0+r)*HD + c0 + s]);
  s16x8 v0, v1;
  #pragma unroll
  for (int e=0;e<8;++e){ v0[e] = (short)tmp[e]; v1[e] = (short)tmp[8+e]; }
  *(s16x8*)(fb + (size_t)(n0+r)*HD + c0)     = v0;
  *(s16x8*)(fb + (size_t)(n0+r)*HD + c0 + 8) = v1;
  #pragma unroll
  for (int s=0;s<16;++s) Ls[c0+s][r] = tmp[s];
  __syncthreads();
  int h = t>>2, n1 = (t&3)*16;
  s16x8 w0, w1;
  #pragma unroll
  for (int e=0;e<8;++e){ w0[e] = (short)Ls[h][n1+e]; w1[e] = (short)Ls[h][n1+8+e]; }
  *(s16x8*)(fbT + (size_t)h*NN + n0 + n1)     = w0;
  *(s16x8*)(fbT + (size_t)h*NN + n0 + n1 + 8) = w1;
}

// ---- 5+6 fused. k_attn: per block = 64 i-rows x 256 j-range.
//      S = fb_i . fb_j via MFMA (A,B both [row][k] from LDS, XOR-swizzled);
//      exp in f32 on accumulators, rowsum partials fused;
//      P f32 -> wave-private swizzled LDS -> bf16 A-frags;
//      PV via MFMA with B-frags from staged fbT tile.
//      LDS: Fj 8K + FjT 8K + P 4x4K = 32 KB -> 4 blocks/CU at grid 1024. ----
__global__ void __launch_bounds__(256)
k_attn(const unsigned short* __restrict__ fb, const unsigned short* __restrict__ fbT,
       float* __restrict__ dpre, float* __restrict__ rowsum){
  __shared__ __align__(16) unsigned char sm[32768];
  const int t  = threadIdx.x;
  const int l  = t & 63;
  const int w  = t >> 6;
  const int g  = l >> 4;
  const int i0 = blockIdx.x*64;
  const int jb0 = blockIdx.y*256;

  // hoist A-frags: rows i0 + w*16 + (l&15), k = g*8 + kk*32  (Q-hoist)
  s16x8 aQ[2];
  {
    const unsigned short* src = fb + (size_t)(i0 + w*16 + (l&15))*HD + g*8;
    aQ[0] = *(const s16x8*)(src);
    aQ[1] = *(const s16x8*)(src + 32);
  }

  f32x4 acco[4];
  #pragma unroll
  for (int nh=0;nh<4;++nh)
    #pragma unroll
    for (int q=0;q<4;++q) acco[nh][q] = 0.f;
  float rsum[4] = {0.f,0.f,0.f,0.f};

  float* Pw = (float*)(sm + 16384 + w*4096);   // wave-private [16][64] f32, swizzled

  for (int jt = 0; jt < 4; ++jt){
    int j0 = jb0 + jt*64;
    __syncthreads();   // prior tile's LDS reads done in all waves
    #pragma unroll
    for (int p = 0; p < 2; ++p){
      int r  = p*32 + (t>>3);
      int cs = ((t&7) ^ (r&7))*8;   // inverse-swizzled source -> linear LDS dest
      __builtin_amdgcn_global_load_lds(
        (const __attribute__((address_space(1))) void*)(fb + (size_t)(j0+r)*HD + cs),
        (__attribute__((address_space(3))) void*)(sm + p*4096 + t*16), 16, 0, 0);
      __builtin_amdgcn_global_load_lds(
        (const __attribute__((address_space(1))) void*)(fbT + (size_t)r*NN + j0 + cs),
        (__attribute__((address_space(3))) void*)(sm + 8192 + p*4096 + t*16), 16, 0, 0);
    }
    __syncthreads();   // drains vmcnt(0): staged tiles visible

    // S tile: C[i][j], i = wave's 16 rows, j = 64
    f32x4 accs[4];
    #pragma unroll
    for (int nj=0;nj<4;++nj)
      #pragma unroll
      for (int q=0;q<4;++q) accs[nj][q] = 0.f;
    #pragma unroll
    for (int kk=0; kk<2; ++kk){
      int s = kk*4 + g;
      #pragma unroll
      for (int nj=0;nj<4;++nj){
        int row = nj*16 + (l&15);
        s16x8 b = *(const s16x8*)(sm + row*128 + ((s ^ (row&7))*16));
        accs[nj] = __builtin_amdgcn_mfma_f32_16x16x32_bf16(aQ[kk], b, accs[nj], 0,0,0);
      }
    }

    // exp + rowsum partial + P -> swizzled f32 LDS (C-layout: i=g*4+q, j=nj*16+(l&15))
    #pragma unroll
    for (int q=0;q<4;++q){
      int i  = g*4 + q;
      int sw = (i&7)<<2;
      #pragma unroll
      for (int nj=0;nj<4;++nj){
        float p = __expf(accs[nj][q]*0.125f);
        rsum[q] += p;
        Pw[i*64 + ((nj*16 + (l&15)) ^ sw)] = p;
      }
    }

    // PV: A = P (i = l&15, k(j) = g*8 + r + kk*32), B = fbT rows (h, k(j))
    #pragma unroll
    for (int kk=0; kk<2; ++kk){
      int i  = l & 15;
      int sw = (i&7)<<2;
      int jb = g*8 + kk*32;
      f32x4 va = *(const f32x4*)(Pw + i*64 + ( jb      ^ sw));
      f32x4 vb = *(const f32x4*)(Pw + i*64 + ((jb + 4) ^ sw));
      s16x8 pa;
      #pragma unroll
      for (int e=0;e<4;++e){
        float fa = va[e], fbv = vb[e];
        pa[e]   = (short)f2b_rne(fa);
        pa[4+e] = (short)f2b_rne(fbv);
      }
      int s = kk*4 + g;
      #pragma unroll
      for (int nh=0;nh<4;++nh){
        int row = nh*16 + (l&15);
        s16x8 bT = *(const s16x8*)(sm + 8192 + row*128 + ((s ^ (row&7))*16));
        acco[nh] = __builtin_amdgcn_mfma_f32_16x16x32_bf16(pa, bT, acco[nh], 0,0,0);
      }
    }
  }

  // rowsum: reduce across the 16 lanes sharing a row (l&15 varies)
  #pragma unroll
  for (int q=0;q<4;++q){
    float v = rsum[q];
    v += __shfl_xor(v,1); v += __shfl_xor(v,2);
    v += __shfl_xor(v,4); v += __shfl_xor(v,8);
    if ((l&15)==0) atomicAdd(&rowsum[i0 + w*16 + g*4 + q], v);
  }
  // dpre: C-frag map row = g*4+q, col = nh*16+(l&15)
  #pragma unroll
  for (int nh=0;nh<4;++nh)
    #pragma unroll
    for (int q=0;q<4;++q)
      atomicAdd(&dpre[(size_t)(i0 + w*16 + g*4 + q)*HD + nh*16 + (l&15)], acco[nh][q]);
}

// ---- 7. d = LN2(dpre/rowsum); dmat, sq_d ----
__global__ void k_dln(const float* __restrict__ dpre, const float* __restrict__ rowsum,
                      const float* __restrict__ ln2w, const float* __restrict__ ln2b,
                      const float* __restrict__ wow,
                      float* __restrict__ dmat, float* __restrict__ sq_d){
  int lane = threadIdx.x & 63;
  int n = blockIdx.x*4 + (threadIdx.x>>6);
  float x = dpre[(size_t)n*HD + lane] / rowsum[n];
  float tot = x;
  for (int m=32;m>=1;m>>=1) tot += __shfl_xor(tot,m);
  float mean = tot*(1.f/64.f);
  float dv = x - mean;
  float vv = dv*dv;
  for (int m=32;m>=1;m>>=1) vv += __shfl_xor(vv,m);
  float y = dv*(1.f/sqrtf(vv*(1.f/64.f)+1e-5f))*ln2w[lane] + ln2b[lane];
  dmat[(size_t)n*HD + lane] = y;
  float wv = wow[lane];
  float q = wv*y*y;
  for (int m=32;m>=1;m>>=1) q += __shfl_xor(q,m);
  if (lane==0) sq_d[n] = q;
}

// ---- 8. Hm[n][e] = exp(-(sq_s[e]+sq_d[n]-2*dot(sw[e],d[n])+b)/800), store bf16 ----
__global__ void k_hm(const float* __restrict__ dmat, const float* __restrict__ sw,
                     const float* __restrict__ sq_d, const float* __restrict__ sq_s,
                     const float* __restrict__ wob, bf16* __restrict__ Hm){
  __shared__ float As[64][65]; // [k(h)][m(n)]
  __shared__ float Bs[64][65]; // [k(h)][n(e)]
  int n0 = blockIdx.x*64, e0 = blockIdx.y*64;
  int tid=threadIdx.x, tx=tid&15, ty=tid>>4;
  for (int idx=tid; idx<4096; idx+=256){
    int r=idx>>6, c=idx&63;
    As[c][r] = dmat[(size_t)(n0+r)*HD + c];
    Bs[c][r] = sw  [(size_t)(e0+r)*HD + c];
  }
  __syncthreads();
  float acc[4][4]={};
  for (int k=0;k<64;++k){
    float a[4], b[4];
    #pragma unroll
    for (int i=0;i<4;++i) a[i] = As[k][tx*4+i];
    #pragma unroll
    for (int i=0;i<4;++i) b[i] = Bs[k][ty*4+i];
    #pragma unroll
    for (int mi=0;mi<4;++mi)
      #pragma unroll
      for (int ni=0;ni<4;++ni) acc[mi][ni] += a[mi]*b[ni];
  }
  float bias = wob[0];
  for (int mi=0;mi<4;++mi)
    for (int ni=0;ni<4;++ni){
      int nn = n0+tx*4+mi, ee = e0+ty*4+ni;
      float ta = sq_s[ee] + sq_d[nn] - 2.f*acc[mi][ni] + bias;
      float arg = -ta*(1.f/800.f);
      if (!(arg > -88.f)) arg = -88.f;
      if (arg > 60.f)     arg = 60.f;
      Hm[(size_t)nn*NE + ee] = __float2bfloat16(__expf(arg));
    }
}

// ---- 9. invDV[n] = (row sum of Hm)^-0.5 ----
__global__ void k_dv(const bf16* __restrict__ Hm, float* __restrict__ invDV){
  __shared__ float sm[256];
  int n = blockIdx.x, t = threadIdx.x;
  const bf16* row = Hm + (size_t)n*NE;
  float a = b2f(row[t]) + b2f(row[t+256]) + b2f(row[t+512]) + b2f(row[t+768]);
  sm[t]=a; __syncthreads();
  for (int s=128;s>0;s>>=1){ if(t<s) sm[t]+=sm[t+s]; __syncthreads(); }
  if (t==0){ float v = sm[0]; invDV[n] = (v>0.f) ? 1.f/sqrtf(v) : 0.f; }
}

// ---- 10. DE col sums -> rsqrt(DE) ----
__global__ void k_de(const bf16* __restrict__ Hm, float* __restrict__ DE){
  int e  = blockIdx.x*256 + threadIdx.x;
  int i0 = blockIdx.y*128;
  float acc=0.f;
  for (int i=0;i<128;++i) acc += b2f(Hm[(size_t)(i0+i)*NE + e]);
  atomicAdd(&DE[e], acc);
}
__global__ void k_invde(float* __restrict__ DE){
  int e = blockIdx.x*256 + threadIdx.x;
  float v = DE[e];
  DE[e] = (v>0.f) ? rsqrtf(v) : 0.f;   // sqrt(1/DE): A2@A2^T gives Hm*invDE*Hm^T
}

// ---- 10b. In-place: A2[n][e] = Hm[n][e] * rsqrt(DE[e]) ----
__global__ void k_scale(bf16* __restrict__ Hm, const float* __restrict__ rde){
  int idx = blockIdx.x*256 + threadIdx.x;
  int row = idx >> 7, c8 = idx & 127;
  size_t base = (size_t)row*NE + c8*8;
  s16x8 v = *(const s16x8*)(Hm + base);
  s16x8 o;
  #pragma unroll
  for (int j = 0; j < 8; ++j){
    unsigned int ww = ((unsigned int)(unsigned short)v[j]) << 16;
    float fv; __builtin_memcpy(&fv, &ww, 4);
    fv *= rde[c8*8 + j];
    o[j] = (short)f2b_rne(fv);
  }
  *(s16x8*)(Hm + base) = o;
}

// ---- 11. out = 0.99*G + 0.01*invDV_i*invDV_j*(A2 @ A2^T)  -- bf16 MFMA GEMM. ----
__global__ void __launch_bounds__(256)
k_final(const bf16* __restrict__ A2, const float* __restrict__ invDV,
        const float* __restrict__ G, float* __restrict__ out){
  int bi = blockIdx.x, bj = blockIdx.y;
  if (bj < bi) return;
  __shared__ __align__(16) unsigned char smraw[2*64*65*4];
  const int t    = threadIdx.x;
  const int lane = t & 63;
  const int w    = t >> 6;
  const int wr   = w >> 1, wc = w & 1;
  const int i0 = bi*128, j0 = bj*128;
  const int seg   = t & 7;
  const int rbase = t >> 3;

  f32x4 acc[4][4] = {};

  for (int k0 = 0; k0 < NE; k0 += 64){
    #pragma unroll
    for (int it = 0; it < 4; ++it){
      int r  = it*32 + rbase;
      int ss = seg ^ (r & 7);
      const bf16* ga = A2 + (size_t)(i0 + r)*NE + k0 + ss*8;
      const bf16* gb = A2 + (size_t)(j0 + r)*NE + k0 + ss*8;
      __builtin_amdgcn_global_load_lds(
        (const __attribute__((address_space(1))) void*)ga,
        (__attribute__((address_space(3))) void*)(smraw + it*4096 + t*16), 16, 0, 0);
      __builtin_amdgcn_global_load_lds(
        (const __attribute__((address_space(1))) void*)gb,
        (__attribute__((address_space(3))) void*)(smraw + 16384 + it*4096 + t*16), 16, 0, 0);
    }
    __syncthreads();
    #pragma unroll
    for (int kk = 0; kk < 2; ++kk){
      s16x8 a[4], b[4];
      #pragma unroll
      for (int mi = 0; mi < 4; ++mi){
        int row = wr*64 + mi*16 + (lane & 15);
        int s   = kk*4 + (lane >> 4);
        a[mi] = *(const s16x8*)(smraw + row*128 + ((s ^ (row & 7))*16));
      }
      #pragma unroll
      for (int ni = 0; ni < 4; ++ni){
        int row = wc*64 + ni*16 + (lane & 15);
        int s   = kk*4 + (lane >> 4);
        b[ni] = *(const s16x8*)(smraw + 16384 + row*128 + ((s ^ (row & 7))*16));
      }
      #pragma unroll
      for (int mi = 0; mi < 4; ++mi)
        #pragma unroll
        for (int ni = 0; ni < 4; ++ni)
          acc[mi][ni] = __builtin_amdgcn_mfma_f32_16x16x32_bf16(a[mi], b[ni], acc[mi][ni], 0, 0, 0);
    }
    __syncthreads();
  }

  float dvi[4][4], dvj[4];
  #pragma unroll
  for (int mi = 0; mi < 4; ++mi)
    #pragma unroll
    for (int q = 0; q < 4; ++q)
      dvi[mi][q] = invDV[i0 + wr*64 + mi*16 + (lane>>4)*4 + q];
  #pragma unroll
  for (int ni = 0; ni < 4; ++ni)
    dvj[ni] = invDV[j0 + wc*64 + ni*16 + (lane & 15)];

  #pragma unroll
  for (int mi = 0; mi < 4; ++mi)
    #pragma unroll
    for (int q = 0; q < 4; ++q){
      int ii = i0 + wr*64 + mi*16 + (lane>>4)*4 + q;
      #pragma unroll
      for (int ni = 0; ni < 4; ++ni){
        int jj = j0 + wc*64 + ni*16 + (lane & 15);
        size_t o = (size_t)ii*NN + jj;
        out[o] = 0.99f*G[o] + 0.01f*(dvi[mi][q]*dvj[ni]*acc[mi][ni][q]);
      }
    }

  if (bi == bj) return;
  float (*Mir)[64][65] = (float(*)[64][65])smraw;
  for (int p = 0; p < 2; ++p){
    if (wr == p){
      #pragma unroll
      for (int mi = 0; mi < 4; ++mi)
        #pragma unroll
        for (int ni = 0; ni < 4; ++ni)
          #pragma unroll
          for (int q = 0; q < 4; ++q)
            Mir[wc][ni*16 + (lane & 15)][mi*16 + (lane>>4)*4 + q] =
              0.01f*(dvi[mi][q]*dvj[ni]*acc[mi][ni][q]);
    }
    __syncthreads();
    #pragma unroll
    for (int b = 0; b < 2; ++b){
      for (int itr = 0; itr < 16; ++itr){
        int idx = itr*256 + t;
        int jl = idx >> 6, il = idx & 63;
        size_t o = (size_t)(j0 + b*64 + jl)*NN + (i0 + p*64 + il);
        out[o] = 0.99f*G[o] + Mir[b][jl][il];
      }
    }
    __syncthreads();
  }
}

extern "C" void kernel_launch(void* const* d_in, const int* in_sizes, int n_in,
                              void* d_out, int out_size, void* d_ws, size_t ws_size,
                              hipStream_t stream){
  const float* adj  = (const float*)d_in[0];
  const float* G    = (const float*)d_in[1];
  const float* feats= (const float*)d_in[2];
  const float* Wv   = (const float*)d_in[3];
  const float* lin  = (const float*)d_in[4];
  const float* wow  = (const float*)d_in[5];
  const float* wob  = (const float*)d_in[6];
  const float* ln1w = (const float*)d_in[7];
  const float* ln1b = (const float*)d_in[8];
  const float* ln2w = (const float*)d_in[9];
  const float* ln2b = (const float*)d_in[10];
  float* out = (float*)d_out;

  float* w = (float*)d_ws;
  float* colsum = w; w += NE;
  float* DE     = w; w += NE;   // becomes rsqrt(DE) in place
  float* sq_s   = w; w += NE;
  float* rowsum = w; w += NN;
  float* sq_d   = w; w += NN;
  float* invDV  = w; w += NN;
  float* ecT    = w; w += NE*DIN;
  float* swp    = w; w += NE*HD;
  float* f      = w; w += NN*HD;
  float* dpre   = w; w += NN*HD;
  float* dmat   = w; w += NN*HD;
  unsigned short* fbm  = (unsigned short*)w; w += NN*HD/2;   // bf16 f
  unsigned short* fbT  = (unsigned short*)w; w += NN*HD/2;   // bf16 f^T (64 x 4096)
  bf16*  Hm     = (bf16*)w;     // NN*NE bf16 = 8 MB

  hipMemsetAsync(colsum, 0, NE*sizeof(float), stream);
  hipMemsetAsync(DE,     0, NE*sizeof(float), stream);
  hipMemsetAsync(rowsum, 0, NN*sizeof(float), stream);
  hipMemsetAsync(ecT,    0, (size_t)NE*DIN*sizeof(float), stream);
  hipMemsetAsync(f,      0, (size_t)NN*HD*sizeof(float), stream);
  hipMemsetAsync(dpre,   0, (size_t)NN*HD*sizeof(float), stream);

  k_colsum <<<dim3(4,32),    256, 0, stream>>>(adj, colsum);
  k_ect    <<<dim3(4,16,16), 256, 0, stream>>>(feats, adj, ecT);
  k_s      <<<NE,             64, 0, stream>>>(ecT, colsum, lin, ln1w, ln1b, wow, swp, sq_s);
  k_f      <<<dim3(64,4),    256, 0, stream>>>(feats, Wv, f);
  k_f2b    <<<64,            256, 0, stream>>>(f, fbm, fbT);
  k_attn   <<<dim3(64,16),   256, 0, stream>>>(fbm, fbT, dpre, rowsum);
  k_dln    <<<NN/4,          256, 0, stream>>>(dpre, rowsum, ln2w, ln2b, wow, dmat, sq_d);
  k_hm     <<<dim3(64,16),   256, 0, stream>>>(dmat, swp, sq_d, sq_s, wob, Hm);
  k_dv     <<<NN,            256, 0, stream>>>(Hm, invDV);
  k_de     <<<dim3(4,32),    256, 0, stream>>>(Hm, DE);
  k_invde  <<<4,             256, 0, stream>>>(DE);
  k_scale  <<<2048,          256, 0, stream>>>(Hm, DE);
  k_final  <<<dim3(32,32),   256, 0, stream>>>(Hm, invDV, G, out);
}

// Round 3
// 354.227 us; speedup vs baseline: 2.9812x; 1.2385x over previous
//
#include <hip/hip_runtime.h>
#include <hip/hip_bf16.h>
#include <math.h>

#define NN 4096
#define NE 1024
#define DIN 256
#define HD 64

typedef __hip_bfloat16 bf16;
__device__ __forceinline__ float b2f(bf16 x){ return __bfloat162float(x); }

typedef __attribute__((ext_vector_type(8))) short s16x8;   // 8 bf16 = 4 VGPR
typedef __attribute__((ext_vector_type(4))) float f32x4;   // MFMA 16x16 acc

__device__ __forceinline__ unsigned short f2b_rne(float x){  // RNE f32->bf16 (finite)
  unsigned u; __builtin_memcpy(&u, &x, 4);
  u += 0x7fff + ((u>>16)&1);
  return (unsigned short)(u>>16);
}

// Stage 128 rows x 64 k (2B elems) of A and B into LDS (linear dest, inverse-swizzled src).
// Uses local names: t. PA/PB pre-offset to tile row 0.
#define STAGE128(dstbase, PA, strideA, PB, strideB, k0) do{ \
  _Pragma("unroll") \
  for (int it_ = 0; it_ < 4; ++it_){ \
    int r_  = it_*32 + (t>>3); \
    int ss_ = ((t&7) ^ (r_&7))*8; \
    __builtin_amdgcn_global_load_lds( \
      (const __attribute__((address_space(1))) void*)((PA) + (size_t)r_*(strideA) + (k0) + ss_), \
      (__attribute__((address_space(3))) void*)((dstbase) + it_*4096 + t*16), 16, 0, 0); \
    __builtin_amdgcn_global_load_lds( \
      (const __attribute__((address_space(1))) void*)((PB) + (size_t)r_*(strideB) + (k0) + ss_), \
      (__attribute__((address_space(3))) void*)((dstbase) + 16384 + it_*4096 + t*16), 16, 0, 0); \
  } }while(0)

// One BK=64 step: 16 ds_read_b128 (swizzled) + 32 MFMA. Uses: wr, wc, lane, acc.
#define COMPUTE64(base) do{ \
  _Pragma("unroll") \
  for (int kk_ = 0; kk_ < 2; ++kk_){ \
    s16x8 a_[4], b_[4]; \
    _Pragma("unroll") \
    for (int mi_ = 0; mi_ < 4; ++mi_){ \
      int row_ = wr*64 + mi_*16 + (lane & 15); \
      int s_   = kk_*4 + (lane >> 4); \
      a_[mi_] = *(const s16x8*)((base) + row_*128 + ((s_ ^ (row_&7))*16)); \
    } \
    _Pragma("unroll") \
    for (int ni_ = 0; ni_ < 4; ++ni_){ \
      int row_ = wc*64 + ni_*16 + (lane & 15); \
      int s_   = kk_*4 + (lane >> 4); \
      b_[ni_] = *(const s16x8*)((base) + 16384 + row_*128 + ((s_ ^ (row_&7))*16)); \
    } \
    _Pragma("unroll") \
    for (int mi_ = 0; mi_ < 4; ++mi_) \
      _Pragma("unroll") \
      for (int ni_ = 0; ni_ < 4; ++ni_) \
        acc[mi_][ni_] = __builtin_amdgcn_mfma_f32_16x16x32_bf16(a_[mi_], b_[ni_], acc[mi_][ni_], 0, 0, 0); \
  } }while(0)

// ---- 1. transpose f32 -> bf16: dst[c][r] = bf16(src[r][c]); optional col-sum of src.
//      R = gridDim.x*64 (rows of src), C = gridDim.y*64 (cols of src). ----
__global__ void k_t2b(const float* __restrict__ src, unsigned short* __restrict__ dst,
                      float* __restrict__ csum){
  __shared__ float Ls[64][65];
  int R = gridDim.x*64, C = gridDim.y*64;
  int r0 = blockIdx.x*64, c0 = blockIdx.y*64;
  int t = threadIdx.x;
  int lr = t>>2, lc = (t&3)*16;
  #pragma unroll
  for (int s = 0; s < 4; ++s){
    float4 v = *(const float4*)(src + (size_t)(r0+lr)*C + c0 + lc + s*4);
    Ls[lr][lc+s*4+0]=v.x; Ls[lr][lc+s*4+1]=v.y; Ls[lr][lc+s*4+2]=v.z; Ls[lr][lc+s*4+3]=v.w;
  }
  __syncthreads();
  if (csum != nullptr && t < 64){
    float s = 0.f;
    #pragma unroll
    for (int r = 0; r < 64; ++r) s += Ls[r][t];
    atomicAdd(&csum[c0 + t], s);
  }
  int wc = t>>3, wr8 = (t&7)*8;
  #pragma unroll
  for (int p = 0; p < 2; ++p){
    int c = wc + p*32;
    s16x8 o;
    #pragma unroll
    for (int e = 0; e < 8; ++e) o[e] = (short)f2b_rne(Ls[wr8+e][c]);
    *(s16x8*)(dst + (size_t)(c0+c)*R + r0 + wr8) = o;
  }
}

// ---- 2. ecT[e][c] += sum_i feats[i][c]*adj[i][e] -- bf16 MFMA, K-chunked (atomics).
//      A = featsT[c][i] (256 x 4096), B = adjT[e][i] (1024 x 4096). 2-phase dbuf. ----
__global__ void __launch_bounds__(256, 2)
k_ect_mfma(const unsigned short* __restrict__ fT, const unsigned short* __restrict__ aT,
           float* __restrict__ ecT){
  __shared__ __align__(16) unsigned char sm[65536];
  const int t = threadIdx.x, lane = t & 63, w = t >> 6;
  const int wr = w >> 1, wc = w & 1;
  const int m0 = blockIdx.x*128, n0 = blockIdx.y*128, kb = blockIdx.z*256;
  const unsigned short* PA = fT + (size_t)m0*NN + kb;
  const unsigned short* PB = aT + (size_t)n0*NN + kb;
  f32x4 acc[4][4] = {};
  STAGE128(sm, PA, NN, PB, NN, 0);
  __syncthreads();
  int cur = 0;
  for (int kt = 0; kt < 4; ++kt){
    if (kt < 3) STAGE128(sm + (cur^1)*32768, PA, NN, PB, NN, (kt+1)*64);
    COMPUTE64(sm + cur*32768);
    __syncthreads();
    cur ^= 1;
  }
  #pragma unroll
  for (int mi = 0; mi < 4; ++mi)
    #pragma unroll
    for (int q = 0; q < 4; ++q){
      int c = m0 + wr*64 + mi*16 + (lane>>4)*4 + q;
      #pragma unroll
      for (int ni = 0; ni < 4; ++ni){
        int e = n0 + wc*64 + ni*16 + (lane & 15);
        atomicAdd(&ecT[(size_t)e*DIN + c], acc[mi][ni][q]);
      }
    }
}

// ---- 3. s = LN1((ecT/colsum) @ lin_w^T); sw = s*w_o, sq_s = sum_h w*s^2 ----
__global__ void k_s(const float* __restrict__ ecT, const float* __restrict__ colsum,
                    const float* __restrict__ lin_w,
                    const float* __restrict__ ln1w, const float* __restrict__ ln1b,
                    const float* __restrict__ wow,
                    float* __restrict__ sw, float* __restrict__ sq_s){
  int e = blockIdx.x, h = threadIdx.x;
  const float* row = ecT + (size_t)e*DIN;
  const float* lw  = lin_w + (size_t)h*DIN;
  float acc = 0.f;
  for (int c = 0; c < DIN; ++c) acc += row[c]*lw[c];
  acc /= colsum[e];
  float tot = acc;
  for (int m=32;m>=1;m>>=1) tot += __shfl_xor(tot,m);
  float mean = tot*(1.f/64.f);
  float dv = acc - mean;
  float vv = dv*dv;
  for (int m=32;m>=1;m>>=1) vv += __shfl_xor(vv,m);
  float y = dv*(1.f/sqrtf(vv*(1.f/64.f)+1e-5f))*ln1w[h] + ln1b[h];
  float wv = wow[h];
  sw[(size_t)e*HD + h] = y*wv;
  float q = wv*y*y;
  for (int m=32;m>=1;m>>=1) q += __shfl_xor(q,m);
  if (h==0) sq_s[e] = q;
}

// ---- 4. f += feats @ W_v^T over K chunk ----
__global__ void k_f(const float* __restrict__ feats, const float* __restrict__ Wv,
                    float* __restrict__ f){
  __shared__ float As[64][65]; // [k(c)][m(i)]
  __shared__ float Bs[64][65]; // [k(c)][n(h)]
  int i0 = blockIdx.x*64;
  int c0 = blockIdx.y*64;
  int tid=threadIdx.x, tx=tid&15, ty=tid>>4;
  float acc[4][4]={};
  for (int idx=tid; idx<4096; idx+=256){
    int r=idx>>6, c=idx&63;
    As[c][r] = feats[(size_t)(i0+r)*DIN + c0+c];
    Bs[c][r] = Wv   [(size_t)r*DIN      + c0+c];
  }
  __syncthreads();
  for (int k=0;k<64;++k){
    float a[4], b[4];
    #pragma unroll
    for (int i=0;i<4;++i) a[i] = As[k][tx*4+i];
    #pragma unroll
    for (int i=0;i<4;++i) b[i] = Bs[k][ty*4+i];
    #pragma unroll
    for (int mi=0;mi<4;++mi)
      #pragma unroll
      for (int ni=0;ni<4;++ni) acc[mi][ni] += a[mi]*b[ni];
  }
  for (int mi=0;mi<4;++mi)
    for (int ni=0;ni<4;++ni)
      atomicAdd(&f[(size_t)(i0+tx*4+mi)*HD + ty*4+ni], acc[mi][ni]);
}

// ---- 4b. fb = bf16(f), fbT = bf16(f)^T (64x4096, h-major) for the MFMA attn ----
__global__ void k_f2b(const float* __restrict__ f, unsigned short* __restrict__ fb,
                      unsigned short* __restrict__ fbT){
  __shared__ unsigned short Ls[64][72];
  int n0 = blockIdx.x*64;
  int t = threadIdx.x;
  int r = t>>2, c0 = (t&3)*16;
  unsigned short tmp[16];
  #pragma unroll
  for (int s=0;s<16;++s) tmp[s] = f2b_rne(f[(size_t)(n0+r)*HD + c0 + s]);
  s16x8 v0, v1;
  #pragma unroll
  for (int e=0;e<8;++e){ v0[e] = (short)tmp[e]; v1[e] = (short)tmp[8+e]; }
  *(s16x8*)(fb + (size_t)(n0+r)*HD + c0)     = v0;
  *(s16x8*)(fb + (size_t)(n0+r)*HD + c0 + 8) = v1;
  #pragma unroll
  for (int s=0;s<16;++s) Ls[c0+s][r] = tmp[s];
  __syncthreads();
  int h = t>>2, n1 = (t&3)*16;
  s16x8 w0, w1;
  #pragma unroll
  for (int e=0;e<8;++e){ w0[e] = (short)Ls[h][n1+e]; w1[e] = (short)Ls[h][n1+8+e]; }
  *(s16x8*)(fbT + (size_t)h*NN + n0 + n1)     = w0;
  *(s16x8*)(fbT + (size_t)h*NN + n0 + n1 + 8) = w1;
}

// ---- 5+6 fused MFMA attention (S, exp, rowsum, PV) ----
__global__ void __launch_bounds__(256)
k_attn(const unsigned short* __restrict__ fb, const unsigned short* __restrict__ fbT,
       float* __restrict__ dpre, float* __restrict__ rowsum){
  __shared__ __align__(16) unsigned char sm[32768];
  const int t  = threadIdx.x;
  const int l  = t & 63;
  const int w  = t >> 6;
  const int g  = l >> 4;
  const int i0 = blockIdx.x*64;
  const int jb0 = blockIdx.y*256;

  s16x8 aQ[2];
  {
    const unsigned short* src = fb + (size_t)(i0 + w*16 + (l&15))*HD + g*8;
    aQ[0] = *(const s16x8*)(src);
    aQ[1] = *(const s16x8*)(src + 32);
  }

  f32x4 acco[4];
  #pragma unroll
  for (int nh=0;nh<4;++nh)
    #pragma unroll
    for (int q=0;q<4;++q) acco[nh][q] = 0.f;
  float rsum[4] = {0.f,0.f,0.f,0.f};

  float* Pw = (float*)(sm + 16384 + w*4096);

  for (int jt = 0; jt < 4; ++jt){
    int j0 = jb0 + jt*64;
    __syncthreads();
    #pragma unroll
    for (int p = 0; p < 2; ++p){
      int r  = p*32 + (t>>3);
      int cs = ((t&7) ^ (r&7))*8;
      __builtin_amdgcn_global_load_lds(
        (const __attribute__((address_space(1))) void*)(fb + (size_t)(j0+r)*HD + cs),
        (__attribute__((address_space(3))) void*)(sm + p*4096 + t*16), 16, 0, 0);
      __builtin_amdgcn_global_load_lds(
        (const __attribute__((address_space(1))) void*)(fbT + (size_t)r*NN + j0 + cs),
        (__attribute__((address_space(3))) void*)(sm + 8192 + p*4096 + t*16), 16, 0, 0);
    }
    __syncthreads();

    f32x4 accs[4];
    #pragma unroll
    for (int nj=0;nj<4;++nj)
      #pragma unroll
      for (int q=0;q<4;++q) accs[nj][q] = 0.f;
    #pragma unroll
    for (int kk=0; kk<2; ++kk){
      int s = kk*4 + g;
      #pragma unroll
      for (int nj=0;nj<4;++nj){
        int row = nj*16 + (l&15);
        s16x8 b = *(const s16x8*)(sm + row*128 + ((s ^ (row&7))*16));
        accs[nj] = __builtin_amdgcn_mfma_f32_16x16x32_bf16(aQ[kk], b, accs[nj], 0,0,0);
      }
    }

    #pragma unroll
    for (int q=0;q<4;++q){
      int i  = g*4 + q;
      int sw = (i&7)<<2;
      #pragma unroll
      for (int nj=0;nj<4;++nj){
        float p = __expf(accs[nj][q]*0.125f);
        rsum[q] += p;
        Pw[i*64 + ((nj*16 + (l&15)) ^ sw)] = p;
      }
    }

    #pragma unroll
    for (int kk=0; kk<2; ++kk){
      int i  = l & 15;
      int sw = (i&7)<<2;
      int jb = g*8 + kk*32;
      f32x4 va = *(const f32x4*)(Pw + i*64 + ( jb      ^ sw));
      f32x4 vb = *(const f32x4*)(Pw + i*64 + ((jb + 4) ^ sw));
      s16x8 pa;
      #pragma unroll
      for (int e=0;e<4;++e){
        float fa = va[e], fbv = vb[e];
        pa[e]   = (short)f2b_rne(fa);
        pa[4+e] = (short)f2b_rne(fbv);
      }
      int s = kk*4 + g;
      #pragma unroll
      for (int nh=0;nh<4;++nh){
        int row = nh*16 + (l&15);
        s16x8 bT = *(const s16x8*)(sm + 8192 + row*128 + ((s ^ (row&7))*16));
        acco[nh] = __builtin_amdgcn_mfma_f32_16x16x32_bf16(pa, bT, acco[nh], 0,0,0);
      }
    }
  }

  #pragma unroll
  for (int q=0;q<4;++q){
    float v = rsum[q];
    v += __shfl_xor(v,1); v += __shfl_xor(v,2);
    v += __shfl_xor(v,4); v += __shfl_xor(v,8);
    if ((l&15)==0) atomicAdd(&rowsum[i0 + w*16 + g*4 + q], v);
  }
  #pragma unroll
  for (int nh=0;nh<4;++nh)
    #pragma unroll
    for (int q=0;q<4;++q)
      atomicAdd(&dpre[(size_t)(i0 + w*16 + g*4 + q)*HD + nh*16 + (l&15)], acco[nh][q]);
}

// ---- 7. d = LN2(dpre/rowsum); dmat, sq_d ----
__global__ void k_dln(const float* __restrict__ dpre, const float* __restrict__ rowsum,
                      const float* __restrict__ ln2w, const float* __restrict__ ln2b,
                      const float* __restrict__ wow,
                      float* __restrict__ dmat, float* __restrict__ sq_d){
  int lane = threadIdx.x & 63;
  int n = blockIdx.x*4 + (threadIdx.x>>6);
  float x = dpre[(size_t)n*HD + lane] / rowsum[n];
  float tot = x;
  for (int m=32;m>=1;m>>=1) tot += __shfl_xor(tot,m);
  float mean = tot*(1.f/64.f);
  float dv = x - mean;
  float vv = dv*dv;
  for (int m=32;m>=1;m>>=1) vv += __shfl_xor(vv,m);
  float y = dv*(1.f/sqrtf(vv*(1.f/64.f)+1e-5f))*ln2w[lane] + ln2b[lane];
  dmat[(size_t)n*HD + lane] = y;
  float wv = wow[lane];
  float q = wv*y*y;
  for (int m=32;m>=1;m>>=1) q += __shfl_xor(q,m);
  if (lane==0) sq_d[n] = q;
}

// ---- 8. Hm[n][e] = exp(-(sq_s[e]+sq_d[n]-2*dot(sw[e],d[n])+b)/800), store bf16 ----
__global__ void k_hm(const float* __restrict__ dmat, const float* __restrict__ sw,
                     const float* __restrict__ sq_d, const float* __restrict__ sq_s,
                     const float* __restrict__ wob, bf16* __restrict__ Hm){
  __shared__ float As[64][65]; // [k(h)][m(n)]
  __shared__ float Bs[64][65]; // [k(h)][n(e)]
  int n0 = blockIdx.x*64, e0 = blockIdx.y*64;
  int tid=threadIdx.x, tx=tid&15, ty=tid>>4;
  for (int idx=tid; idx<4096; idx+=256){
    int r=idx>>6, c=idx&63;
    As[c][r] = dmat[(size_t)(n0+r)*HD + c];
    Bs[c][r] = sw  [(size_t)(e0+r)*HD + c];
  }
  __syncthreads();
  float acc[4][4]={};
  for (int k=0;k<64;++k){
    float a[4], b[4];
    #pragma unroll
    for (int i=0;i<4;++i) a[i] = As[k][tx*4+i];
    #pragma unroll
    for (int i=0;i<4;++i) b[i] = Bs[k][ty*4+i];
    #pragma unroll
    for (int mi=0;mi<4;++mi)
      #pragma unroll
      for (int ni=0;ni<4;++ni) acc[mi][ni] += a[mi]*b[ni];
  }
  float bias = wob[0];
  for (int mi=0;mi<4;++mi)
    for (int ni=0;ni<4;++ni){
      int nn = n0+tx*4+mi, ee = e0+ty*4+ni;
      float ta = sq_s[ee] + sq_d[nn] - 2.f*acc[mi][ni] + bias;
      float arg = -ta*(1.f/800.f);
      if (!(arg > -88.f)) arg = -88.f;
      if (arg > 60.f)     arg = 60.f;
      Hm[(size_t)nn*NE + ee] = __float2bfloat16(__expf(arg));
    }
}

// ---- 9. invDV[n] = (row sum of Hm)^-0.5 ----
__global__ void k_dv(const bf16* __restrict__ Hm, float* __restrict__ invDV){
  __shared__ float sm[256];
  int n = blockIdx.x, t = threadIdx.x;
  const bf16* row = Hm + (size_t)n*NE;
  float a = b2f(row[t]) + b2f(row[t+256]) + b2f(row[t+512]) + b2f(row[t+768]);
  sm[t]=a; __syncthreads();
  for (int s=128;s>0;s>>=1){ if(t<s) sm[t]+=sm[t+s]; __syncthreads(); }
  if (t==0){ float v = sm[0]; invDV[n] = (v>0.f) ? 1.f/sqrtf(v) : 0.f; }
}

// ---- 10. DE col sums -> rsqrt(DE) ----
__global__ void k_de(const bf16* __restrict__ Hm, float* __restrict__ DE){
  int e  = blockIdx.x*256 + threadIdx.x;
  int i0 = blockIdx.y*128;
  float acc=0.f;
  for (int i=0;i<128;++i) acc += b2f(Hm[(size_t)(i0+i)*NE + e]);
  atomicAdd(&DE[e], acc);
}
__global__ void k_invde(float* __restrict__ DE){
  int e = blockIdx.x*256 + threadIdx.x;
  float v = DE[e];
  DE[e] = (v>0.f) ? rsqrtf(v) : 0.f;
}

// ---- 10b. In-place: A2[n][e] = Hm[n][e] * rsqrt(DE[e]) ----
__global__ void k_scale(bf16* __restrict__ Hm, const float* __restrict__ rde){
  int idx = blockIdx.x*256 + threadIdx.x;
  int row = idx >> 7, c8 = idx & 127;
  size_t base = (size_t)row*NE + c8*8;
  s16x8 v = *(const s16x8*)(Hm + base);
  s16x8 o;
  #pragma unroll
  for (int j = 0; j < 8; ++j){
    unsigned int ww = ((unsigned int)(unsigned short)v[j]) << 16;
    float fv; __builtin_memcpy(&fv, &ww, 4);
    fv *= rde[c8*8 + j];
    o[j] = (short)f2b_rne(fv);
  }
  *(s16x8*)(Hm + base) = o;
}

// ---- 11. out = 0.99*G + 0.01*invDV_i*invDV_j*(A2 @ A2^T).
//      Compact upper-tri grid (528 blocks) + double-buffered 2-phase K-loop
//      (stage k+1 before compute k; ONE barrier per K-step). ----
__global__ void __launch_bounds__(256, 2)
k_final(const bf16* __restrict__ A2, const float* __restrict__ invDV,
        const float* __restrict__ G, float* __restrict__ out){
  __shared__ __align__(16) unsigned char sm[65536];
  const int t    = threadIdx.x;
  const int lane = t & 63;
  const int w    = t >> 6;
  const int wr   = w >> 1, wc = w & 1;

  // triangular index -> (bi, bj), bj >= bi;  S(bi) = 32*bi - bi*(bi-1)/2
  int idx = blockIdx.x;
  int bi = (int)(32.5f - sqrtf(32.5f*32.5f - 2.f*(float)idx));
  while ((bi+1)*32 - ((bi+1)*bi)/2 <= idx) ++bi;
  while (bi*32 - (bi*(bi-1))/2 > idx) --bi;
  int bj = bi + (idx - (bi*32 - (bi*(bi-1))/2));
  const int i0 = bi*128, j0 = bj*128;

  const bf16* PA = A2 + (size_t)i0*NE;
  const bf16* PB = A2 + (size_t)j0*NE;

  f32x4 acc[4][4] = {};
  STAGE128(sm, PA, NE, PB, NE, 0);
  __syncthreads();
  int cur = 0;
  for (int kt = 0; kt < 16; ++kt){
    if (kt < 15) STAGE128(sm + (cur^1)*32768, PA, NE, PB, NE, (kt+1)*64);
    COMPUTE64(sm + cur*32768);
    __syncthreads();
    cur ^= 1;
  }

  float dvi[4][4], dvj[4];
  #pragma unroll
  for (int mi = 0; mi < 4; ++mi)
    #pragma unroll
    for (int q = 0; q < 4; ++q)
      dvi[mi][q] = invDV[i0 + wr*64 + mi*16 + (lane>>4)*4 + q];
  #pragma unroll
  for (int ni = 0; ni < 4; ++ni)
    dvj[ni] = invDV[j0 + wc*64 + ni*16 + (lane & 15)];

  #pragma unroll
  for (int mi = 0; mi < 4; ++mi)
    #pragma unroll
    for (int q = 0; q < 4; ++q){
      int ii = i0 + wr*64 + mi*16 + (lane>>4)*4 + q;
      #pragma unroll
      for (int ni = 0; ni < 4; ++ni){
        int jj = j0 + wc*64 + ni*16 + (lane & 15);
        size_t o = (size_t)ii*NN + jj;
        out[o] = 0.99f*G[o] + 0.01f*(dvi[mi][q]*dvj[ni]*acc[mi][ni][q]);
      }
    }

  if (bi == bj) return;
  float (*Mir)[64][65] = (float(*)[64][65])sm;
  for (int p = 0; p < 2; ++p){
    if (wr == p){
      #pragma unroll
      for (int mi = 0; mi < 4; ++mi)
        #pragma unroll
        for (int ni = 0; ni < 4; ++ni)
          #pragma unroll
          for (int q = 0; q < 4; ++q)
            Mir[wc][ni*16 + (lane & 15)][mi*16 + (lane>>4)*4 + q] =
              0.01f*(dvi[mi][q]*dvj[ni]*acc[mi][ni][q]);
    }
    __syncthreads();
    #pragma unroll
    for (int b = 0; b < 2; ++b){
      for (int itr = 0; itr < 16; ++itr){
        int idx2 = itr*256 + t;
        int jl = idx2 >> 6, il = idx2 & 63;
        size_t o = (size_t)(j0 + b*64 + jl)*NN + (i0 + p*64 + il);
        out[o] = 0.99f*G[o] + Mir[b][jl][il];
      }
    }
    __syncthreads();
  }
}

extern "C" void kernel_launch(void* const* d_in, const int* in_sizes, int n_in,
                              void* d_out, int out_size, void* d_ws, size_t ws_size,
                              hipStream_t stream){
  const float* adj  = (const float*)d_in[0];
  const float* G    = (const float*)d_in[1];
  const float* feats= (const float*)d_in[2];
  const float* Wv   = (const float*)d_in[3];
  const float* lin  = (const float*)d_in[4];
  const float* wow  = (const float*)d_in[5];
  const float* wob  = (const float*)d_in[6];
  const float* ln1w = (const float*)d_in[7];
  const float* ln1b = (const float*)d_in[8];
  const float* ln2w = (const float*)d_in[9];
  const float* ln2b = (const float*)d_in[10];
  float* out = (float*)d_out;

  float* w = (float*)d_ws;
  float* colsum = w; w += NE;
  float* DE     = w; w += NE;   // becomes rsqrt(DE) in place
  float* sq_s   = w; w += NE;
  float* rowsum = w; w += NN;
  float* sq_d   = w; w += NN;
  float* invDV  = w; w += NN;
  float* ecT    = w; w += NE*DIN;
  float* swp    = w; w += NE*HD;
  float* f      = w; w += NN*HD;
  float* dpre   = w; w += NN*HD;
  float* dmat   = w; w += NN*HD;
  unsigned short* fbm    = (unsigned short*)w; w += NN*HD/2;   // bf16 f
  unsigned short* fbT    = (unsigned short*)w; w += NN*HD/2;   // bf16 f^T
  unsigned short* featsT = (unsigned short*)w; w += NN*DIN/2;  // bf16 feats^T (256 x 4096)
  bf16*  Hm     = (bf16*)w;     // NN*NE bf16 = 8 MB
  unsigned short* adjT = (unsigned short*)Hm;  // bf16 adj^T (1024 x 4096) -- aliases Hm:
                                               // dead before k_hm writes Hm (stream-ordered)

  hipMemsetAsync(colsum, 0, NE*sizeof(float), stream);
  hipMemsetAsync(DE,     0, NE*sizeof(float), stream);
  hipMemsetAsync(rowsum, 0, NN*sizeof(float), stream);
  hipMemsetAsync(ecT,    0, (size_t)NE*DIN*sizeof(float), stream);
  hipMemsetAsync(f,      0, (size_t)NN*HD*sizeof(float), stream);
  hipMemsetAsync(dpre,   0, (size_t)NN*HD*sizeof(float), stream);

  k_t2b     <<<dim3(64,4),   256, 0, stream>>>(feats, featsT, nullptr);
  k_t2b     <<<dim3(64,16),  256, 0, stream>>>(adj, adjT, colsum);
  k_ect_mfma<<<dim3(2,8,16), 256, 0, stream>>>(featsT, adjT, ecT);
  k_s       <<<NE,            64, 0, stream>>>(ecT, colsum, lin, ln1w, ln1b, wow, swp, sq_s);
  k_f       <<<dim3(64,4),   256, 0, stream>>>(feats, Wv, f);
  k_f2b     <<<64,           256, 0, stream>>>(f, fbm, fbT);
  k_attn    <<<dim3(64,16),  256, 0, stream>>>(fbm, fbT, dpre, rowsum);
  k_dln     <<<NN/4,         256, 0, stream>>>(dpre, rowsum, ln2w, ln2b, wow, dmat, sq_d);
  k_hm      <<<dim3(64,16),  256, 0, stream>>>(dmat, swp, sq_d, sq_s, wob, Hm);
  k_dv      <<<NN,           256, 0, stream>>>(Hm, invDV);
  k_de      <<<dim3(4,32),   256, 0, stream>>>(Hm, DE);
  k_invde   <<<4,            256, 0, stream>>>(DE);
  k_scale   <<<2048,         256, 0, stream>>>(Hm, DE);
  k_final   <<<528,          256, 0, stream>>>(Hm, invDV, G, out);
}

// Round 4
// 341.643 us; speedup vs baseline: 3.0910x; 1.0368x over previous
//
#include <hip/hip_runtime.h>
#include <hip/hip_bf16.h>
#include <math.h>

#define NN 4096
#define NE 1024
#define DIN 256
#define HD 64

typedef __hip_bfloat16 bf16;
__device__ __forceinline__ float b2f(bf16 x){ return __bfloat162float(x); }

typedef __attribute__((ext_vector_type(8))) short s16x8;   // 8 bf16 = 4 VGPR
typedef __attribute__((ext_vector_type(4))) float f32x4;   // MFMA 16x16 acc

__device__ __forceinline__ unsigned short f2b_rne(float x){  // RNE f32->bf16 (finite)
  unsigned u; __builtin_memcpy(&u, &x, 4);
  u += 0x7fff + ((u>>16)&1);
  return (unsigned short)(u>>16);
}

// Stage 128 rows x 64 k (2B elems) of A and B into LDS (linear dest, inverse-swizzled src).
#define STAGE128(dstbase, PA, strideA, PB, strideB, k0) do{ \
  _Pragma("unroll") \
  for (int it_ = 0; it_ < 4; ++it_){ \
    int r_  = it_*32 + (t>>3); \
    int ss_ = ((t&7) ^ (r_&7))*8; \
    __builtin_amdgcn_global_load_lds( \
      (const __attribute__((address_space(1))) void*)((PA) + (size_t)r_*(strideA) + (k0) + ss_), \
      (__attribute__((address_space(3))) void*)((dstbase) + it_*4096 + t*16), 16, 0, 0); \
    __builtin_amdgcn_global_load_lds( \
      (const __attribute__((address_space(1))) void*)((PB) + (size_t)r_*(strideB) + (k0) + ss_), \
      (__attribute__((address_space(3))) void*)((dstbase) + 16384 + it_*4096 + t*16), 16, 0, 0); \
  } }while(0)

// One BK=64 step: 16 ds_read_b128 (swizzled) + 32 MFMA. Uses: wr, wc, lane, acc.
#define COMPUTE64(base) do{ \
  _Pragma("unroll") \
  for (int kk_ = 0; kk_ < 2; ++kk_){ \
    s16x8 a_[4], b_[4]; \
    _Pragma("unroll") \
    for (int mi_ = 0; mi_ < 4; ++mi_){ \
      int row_ = wr*64 + mi_*16 + (lane & 15); \
      int s_   = kk_*4 + (lane >> 4); \
      a_[mi_] = *(const s16x8*)((base) + row_*128 + ((s_ ^ (row_&7))*16)); \
    } \
    _Pragma("unroll") \
    for (int ni_ = 0; ni_ < 4; ++ni_){ \
      int row_ = wc*64 + ni_*16 + (lane & 15); \
      int s_   = kk_*4 + (lane >> 4); \
      b_[ni_] = *(const s16x8*)((base) + 16384 + row_*128 + ((s_ ^ (row_&7))*16)); \
    } \
    _Pragma("unroll") \
    for (int mi_ = 0; mi_ < 4; ++mi_) \
      _Pragma("unroll") \
      for (int ni_ = 0; ni_ < 4; ++ni_) \
        acc[mi_][ni_] = __builtin_amdgcn_mfma_f32_16x16x32_bf16(a_[mi_], b_[ni_], acc[mi_][ni_], 0, 0, 0); \
  } }while(0)

// ---- 1. transpose f32 -> bf16: dst[c][r] = bf16(src[r][c]); optional col-sum of src. ----
__global__ void k_t2b(const float* __restrict__ src, unsigned short* __restrict__ dst,
                      float* __restrict__ csum){
  __shared__ float Ls[64][65];
  int R = gridDim.x*64, C = gridDim.y*64;
  int r0 = blockIdx.x*64, c0 = blockIdx.y*64;
  int t = threadIdx.x;
  int lr = t>>2, lc = (t&3)*16;
  #pragma unroll
  for (int s = 0; s < 4; ++s){
    float4 v = *(const float4*)(src + (size_t)(r0+lr)*C + c0 + lc + s*4);
    Ls[lr][lc+s*4+0]=v.x; Ls[lr][lc+s*4+1]=v.y; Ls[lr][lc+s*4+2]=v.z; Ls[lr][lc+s*4+3]=v.w;
  }
  __syncthreads();
  if (csum != nullptr && t < 64){
    float s = 0.f;
    #pragma unroll
    for (int r = 0; r < 64; ++r) s += Ls[r][t];
    atomicAdd(&csum[c0 + t], s);
  }
  int wc = t>>3, wr8 = (t&7)*8;
  #pragma unroll
  for (int p = 0; p < 2; ++p){
    int c = wc + p*32;
    s16x8 o;
    #pragma unroll
    for (int e = 0; e < 8; ++e) o[e] = (short)f2b_rne(Ls[wr8+e][c]);
    *(s16x8*)(dst + (size_t)(c0+c)*R + r0 + wr8) = o;
  }
}

// ---- 2. ecT[e][c] += sum_i feats[i][c]*adj[i][e] -- bf16 MFMA, K-chunked (atomics). ----
__global__ void __launch_bounds__(256, 2)
k_ect_mfma(const unsigned short* __restrict__ fT, const unsigned short* __restrict__ aT,
           float* __restrict__ ecT){
  __shared__ __align__(16) unsigned char sm[65536];
  const int t = threadIdx.x, lane = t & 63, w = t >> 6;
  const int wr = w >> 1, wc = w & 1;
  const int m0 = blockIdx.x*128, n0 = blockIdx.y*128, kb = blockIdx.z*256;
  const unsigned short* PA = fT + (size_t)m0*NN + kb;
  const unsigned short* PB = aT + (size_t)n0*NN + kb;
  f32x4 acc[4][4] = {};
  STAGE128(sm, PA, NN, PB, NN, 0);
  __syncthreads();
  int cur = 0;
  for (int kt = 0; kt < 4; ++kt){
    if (kt < 3) STAGE128(sm + (cur^1)*32768, PA, NN, PB, NN, (kt+1)*64);
    COMPUTE64(sm + cur*32768);
    __syncthreads();
    cur ^= 1;
  }
  #pragma unroll
  for (int mi = 0; mi < 4; ++mi)
    #pragma unroll
    for (int q = 0; q < 4; ++q){
      int c = m0 + wr*64 + mi*16 + (lane>>4)*4 + q;
      #pragma unroll
      for (int ni = 0; ni < 4; ++ni){
        int e = n0 + wc*64 + ni*16 + (lane & 15);
        atomicAdd(&ecT[(size_t)e*DIN + c], acc[mi][ni][q]);
      }
    }
}

// ---- 3. s = LN1((ecT/colsum) @ lin_w^T); swb = bf16(s*w_o), sq_s = sum_h w*s^2 ----
__global__ void k_s(const float* __restrict__ ecT, const float* __restrict__ colsum,
                    const float* __restrict__ lin_w,
                    const float* __restrict__ ln1w, const float* __restrict__ ln1b,
                    const float* __restrict__ wow,
                    unsigned short* __restrict__ swb, float* __restrict__ sq_s){
  int e = blockIdx.x, h = threadIdx.x;
  const float* row = ecT + (size_t)e*DIN;
  const float* lw  = lin_w + (size_t)h*DIN;
  float acc = 0.f;
  for (int c = 0; c < DIN; ++c) acc += row[c]*lw[c];
  acc /= colsum[e];
  float tot = acc;
  for (int m=32;m>=1;m>>=1) tot += __shfl_xor(tot,m);
  float mean = tot*(1.f/64.f);
  float dv = acc - mean;
  float vv = dv*dv;
  for (int m=32;m>=1;m>>=1) vv += __shfl_xor(vv,m);
  float y = dv*(1.f/sqrtf(vv*(1.f/64.f)+1e-5f))*ln1w[h] + ln1b[h];
  float wv = wow[h];
  swb[(size_t)e*HD + h] = f2b_rne(y*wv);
  float q = wv*y*y;
  for (int m=32;m>=1;m>>=1) q += __shfl_xor(q,m);
  if (h==0) sq_s[e] = q;
}

// ---- 4. f += feats @ W_v^T over K chunk ----
__global__ void k_f(const float* __restrict__ feats, const float* __restrict__ Wv,
                    float* __restrict__ f){
  __shared__ float As[64][65]; // [k(c)][m(i)]
  __shared__ float Bs[64][65]; // [k(c)][n(h)]
  int i0 = blockIdx.x*64;
  int c0 = blockIdx.y*64;
  int tid=threadIdx.x, tx=tid&15, ty=tid>>4;
  float acc[4][4]={};
  for (int idx=tid; idx<4096; idx+=256){
    int r=idx>>6, c=idx&63;
    As[c][r] = feats[(size_t)(i0+r)*DIN + c0+c];
    Bs[c][r] = Wv   [(size_t)r*DIN      + c0+c];
  }
  __syncthreads();
  for (int k=0;k<64;++k){
    float a[4], b[4];
    #pragma unroll
    for (int i=0;i<4;++i) a[i] = As[k][tx*4+i];
    #pragma unroll
    for (int i=0;i<4;++i) b[i] = Bs[k][ty*4+i];
    #pragma unroll
    for (int mi=0;mi<4;++mi)
      #pragma unroll
      for (int ni=0;ni<4;++ni) acc[mi][ni] += a[mi]*b[ni];
  }
  for (int mi=0;mi<4;++mi)
    for (int ni=0;ni<4;++ni)
      atomicAdd(&f[(size_t)(i0+tx*4+mi)*HD + ty*4+ni], acc[mi][ni]);
}

// ---- 4b. fb = bf16(f), fbT = bf16(f)^T for the MFMA attn ----
__global__ void k_f2b(const float* __restrict__ f, unsigned short* __restrict__ fb,
                      unsigned short* __restrict__ fbT){
  __shared__ unsigned short Ls[64][72];
  int n0 = blockIdx.x*64;
  int t = threadIdx.x;
  int r = t>>2, c0 = (t&3)*16;
  unsigned short tmp[16];
  #pragma unroll
  for (int s=0;s<16;++s) tmp[s] = f2b_rne(f[(size_t)(n0+r)*HD + c0 + s]);
  s16x8 v0, v1;
  #pragma unroll
  for (int e=0;e<8;++e){ v0[e] = (short)tmp[e]; v1[e] = (short)tmp[8+e]; }
  *(s16x8*)(fb + (size_t)(n0+r)*HD + c0)     = v0;
  *(s16x8*)(fb + (size_t)(n0+r)*HD + c0 + 8) = v1;
  #pragma unroll
  for (int s=0;s<16;++s) Ls[c0+s][r] = tmp[s];
  __syncthreads();
  int h = t>>2, n1 = (t&3)*16;
  s16x8 w0, w1;
  #pragma unroll
  for (int e=0;e<8;++e){ w0[e] = (short)Ls[h][n1+e]; w1[e] = (short)Ls[h][n1+8+e]; }
  *(s16x8*)(fbT + (size_t)h*NN + n0 + n1)     = w0;
  *(s16x8*)(fbT + (size_t)h*NN + n0 + n1 + 8) = w1;
}

// ---- 5+6 fused MFMA attention (S, exp, rowsum, PV) ----
__global__ void __launch_bounds__(256)
k_attn(const unsigned short* __restrict__ fb, const unsigned short* __restrict__ fbT,
       float* __restrict__ dpre, float* __restrict__ rowsum){
  __shared__ __align__(16) unsigned char sm[32768];
  const int t  = threadIdx.x;
  const int l  = t & 63;
  const int w  = t >> 6;
  const int g  = l >> 4;
  const int i0 = blockIdx.x*64;
  const int jb0 = blockIdx.y*256;

  s16x8 aQ[2];
  {
    const unsigned short* src = fb + (size_t)(i0 + w*16 + (l&15))*HD + g*8;
    aQ[0] = *(const s16x8*)(src);
    aQ[1] = *(const s16x8*)(src + 32);
  }

  f32x4 acco[4];
  #pragma unroll
  for (int nh=0;nh<4;++nh)
    #pragma unroll
    for (int q=0;q<4;++q) acco[nh][q] = 0.f;
  float rsum[4] = {0.f,0.f,0.f,0.f};

  float* Pw = (float*)(sm + 16384 + w*4096);

  for (int jt = 0; jt < 4; ++jt){
    int j0 = jb0 + jt*64;
    __syncthreads();
    #pragma unroll
    for (int p = 0; p < 2; ++p){
      int r  = p*32 + (t>>3);
      int cs = ((t&7) ^ (r&7))*8;
      __builtin_amdgcn_global_load_lds(
        (const __attribute__((address_space(1))) void*)(fb + (size_t)(j0+r)*HD + cs),
        (__attribute__((address_space(3))) void*)(sm + p*4096 + t*16), 16, 0, 0);
      __builtin_amdgcn_global_load_lds(
        (const __attribute__((address_space(1))) void*)(fbT + (size_t)r*NN + j0 + cs),
        (__attribute__((address_space(3))) void*)(sm + 8192 + p*4096 + t*16), 16, 0, 0);
    }
    __syncthreads();

    f32x4 accs[4];
    #pragma unroll
    for (int nj=0;nj<4;++nj)
      #pragma unroll
      for (int q=0;q<4;++q) accs[nj][q] = 0.f;
    #pragma unroll
    for (int kk=0; kk<2; ++kk){
      int s = kk*4 + g;
      #pragma unroll
      for (int nj=0;nj<4;++nj){
        int row = nj*16 + (l&15);
        s16x8 b = *(const s16x8*)(sm + row*128 + ((s ^ (row&7))*16));
        accs[nj] = __builtin_amdgcn_mfma_f32_16x16x32_bf16(aQ[kk], b, accs[nj], 0,0,0);
      }
    }

    #pragma unroll
    for (int q=0;q<4;++q){
      int i  = g*4 + q;
      int sw = (i&7)<<2;
      #pragma unroll
      for (int nj=0;nj<4;++nj){
        float p = __expf(accs[nj][q]*0.125f);
        rsum[q] += p;
        Pw[i*64 + ((nj*16 + (l&15)) ^ sw)] = p;
      }
    }

    #pragma unroll
    for (int kk=0; kk<2; ++kk){
      int i  = l & 15;
      int sw = (i&7)<<2;
      int jb = g*8 + kk*32;
      f32x4 va = *(const f32x4*)(Pw + i*64 + ( jb      ^ sw));
      f32x4 vb = *(const f32x4*)(Pw + i*64 + ((jb + 4) ^ sw));
      s16x8 pa;
      #pragma unroll
      for (int e=0;e<4;++e){
        float fa = va[e], fbv = vb[e];
        pa[e]   = (short)f2b_rne(fa);
        pa[4+e] = (short)f2b_rne(fbv);
      }
      int s = kk*4 + g;
      #pragma unroll
      for (int nh=0;nh<4;++nh){
        int row = nh*16 + (l&15);
        s16x8 bT = *(const s16x8*)(sm + 8192 + row*128 + ((s ^ (row&7))*16));
        acco[nh] = __builtin_amdgcn_mfma_f32_16x16x32_bf16(pa, bT, acco[nh], 0,0,0);
      }
    }
  }

  #pragma unroll
  for (int q=0;q<4;++q){
    float v = rsum[q];
    v += __shfl_xor(v,1); v += __shfl_xor(v,2);
    v += __shfl_xor(v,4); v += __shfl_xor(v,8);
    if ((l&15)==0) atomicAdd(&rowsum[i0 + w*16 + g*4 + q], v);
  }
  #pragma unroll
  for (int nh=0;nh<4;++nh)
    #pragma unroll
    for (int q=0;q<4;++q)
      atomicAdd(&dpre[(size_t)(i0 + w*16 + g*4 + q)*HD + nh*16 + (l&15)], acco[nh][q]);
}

// ---- 7. d = LN2(dpre/rowsum); dmatb (bf16), sq_d ----
__global__ void k_dln(const float* __restrict__ dpre, const float* __restrict__ rowsum,
                      const float* __restrict__ ln2w, const float* __restrict__ ln2b,
                      const float* __restrict__ wow,
                      unsigned short* __restrict__ dmatb, float* __restrict__ sq_d){
  int lane = threadIdx.x & 63;
  int n = blockIdx.x*4 + (threadIdx.x>>6);
  float x = dpre[(size_t)n*HD + lane] / rowsum[n];
  float tot = x;
  for (int m=32;m>=1;m>>=1) tot += __shfl_xor(tot,m);
  float mean = tot*(1.f/64.f);
  float dv = x - mean;
  float vv = dv*dv;
  for (int m=32;m>=1;m>>=1) vv += __shfl_xor(vv,m);
  float y = dv*(1.f/sqrtf(vv*(1.f/64.f)+1e-5f))*ln2w[lane] + ln2b[lane];
  dmatb[(size_t)n*HD + lane] = f2b_rne(y);
  float wv = wow[lane];
  float q = wv*y*y;
  for (int m=32;m>=1;m>>=1) q += __shfl_xor(q,m);
  if (lane==0) sq_d[n] = q;
}

// ---- 8. Hm[n][e] = exp(-(sq_s[e]+sq_d[n]-2*dot(sw[e],d[n])+b)/800) -- MFMA.
//      A-frags hoisted from dmatb (global), B staged+swizzled from swb (8 KB LDS).
//      Same verified pattern as k_attn's S-step. ----
__global__ void __launch_bounds__(256)
k_hm(const unsigned short* __restrict__ dmatb, const unsigned short* __restrict__ swb,
     const float* __restrict__ sq_d, const float* __restrict__ sq_s,
     const float* __restrict__ wob, bf16* __restrict__ Hm){
  __shared__ __align__(16) unsigned char sm[8192];
  const int t = threadIdx.x, l = t & 63, w = t >> 6, g = l >> 4;
  const int n0 = blockIdx.x*64, e0 = blockIdx.y*64;
  #pragma unroll
  for (int p = 0; p < 2; ++p){
    int r  = p*32 + (t>>3);
    int cs = ((t&7) ^ (r&7))*8;
    __builtin_amdgcn_global_load_lds(
      (const __attribute__((address_space(1))) void*)(swb + (size_t)(e0+r)*HD + cs),
      (__attribute__((address_space(3))) void*)(sm + p*4096 + t*16), 16, 0, 0);
  }
  s16x8 aQ[2];
  {
    const unsigned short* src = dmatb + (size_t)(n0 + w*16 + (l&15))*HD + g*8;
    aQ[0] = *(const s16x8*)(src);
    aQ[1] = *(const s16x8*)(src + 32);
  }
  f32x4 accs[4];
  #pragma unroll
  for (int nj=0;nj<4;++nj)
    #pragma unroll
    for (int q=0;q<4;++q) accs[nj][q] = 0.f;
  __syncthreads();
  #pragma unroll
  for (int kk=0; kk<2; ++kk){
    int s = kk*4 + g;
    #pragma unroll
    for (int nj=0;nj<4;++nj){
      int row = nj*16 + (l&15);
      s16x8 b = *(const s16x8*)(sm + row*128 + ((s ^ (row&7))*16));
      accs[nj] = __builtin_amdgcn_mfma_f32_16x16x32_bf16(aQ[kk], b, accs[nj], 0,0,0);
    }
  }
  float bias = wob[0];
  float sqd[4];
  #pragma unroll
  for (int q=0;q<4;++q) sqd[q] = sq_d[n0 + w*16 + g*4 + q];
  #pragma unroll
  for (int nj=0;nj<4;++nj){
    int e = e0 + nj*16 + (l&15);
    float sqs = sq_s[e];
    #pragma unroll
    for (int q=0;q<4;++q){
      float ta = sqs + sqd[q] - 2.f*accs[nj][q] + bias;
      float arg = -ta*(1.f/800.f);
      if (!(arg > -88.f)) arg = -88.f;
      if (arg > 60.f)     arg = 60.f;
      int n = n0 + w*16 + g*4 + q;
      Hm[(size_t)n*NE + e] = __float2bfloat16(__expf(arg));
    }
  }
}

// ---- 9. invDV[n] = (row sum of Hm)^-0.5 ----
__global__ void k_dv(const bf16* __restrict__ Hm, float* __restrict__ invDV){
  __shared__ float sm[256];
  int n = blockIdx.x, t = threadIdx.x;
  const bf16* row = Hm + (size_t)n*NE;
  float a = b2f(row[t]) + b2f(row[t+256]) + b2f(row[t+512]) + b2f(row[t+768]);
  sm[t]=a; __syncthreads();
  for (int s=128;s>0;s>>=1){ if(t<s) sm[t]+=sm[t+s]; __syncthreads(); }
  if (t==0){ float v = sm[0]; invDV[n] = (v>0.f) ? 1.f/sqrtf(v) : 0.f; }
}

// ---- 10. DE col sums -> rsqrt(DE) ----
__global__ void k_de(const bf16* __restrict__ Hm, float* __restrict__ DE){
  int e  = blockIdx.x*256 + threadIdx.x;
  int i0 = blockIdx.y*128;
  float acc=0.f;
  for (int i=0;i<128;++i) acc += b2f(Hm[(size_t)(i0+i)*NE + e]);
  atomicAdd(&DE[e], acc);
}
__global__ void k_invde(float* __restrict__ DE){
  int e = blockIdx.x*256 + threadIdx.x;
  float v = DE[e];
  DE[e] = (v>0.f) ? rsqrtf(v) : 0.f;
}

// ---- 10b. In-place: A2[n][e] = Hm[n][e] * rsqrt(DE[e]) ----
__global__ void k_scale(bf16* __restrict__ Hm, const float* __restrict__ rde){
  int idx = blockIdx.x*256 + threadIdx.x;
  int row = idx >> 7, c8 = idx & 127;
  size_t base = (size_t)row*NE + c8*8;
  s16x8 v = *(const s16x8*)(Hm + base);
  s16x8 o;
  #pragma unroll
  for (int j = 0; j < 8; ++j){
    unsigned int ww = ((unsigned int)(unsigned short)v[j]) << 16;
    float fv; __builtin_memcpy(&fv, &ww, 4);
    fv *= rde[c8*8 + j];
    o[j] = (short)f2b_rne(fv);
  }
  *(s16x8*)(Hm + base) = o;
}

// ---- 11. out = 0.99*G + 0.01*invDV_i*invDV_j*(A2 @ A2^T).
//      Compact upper-tri grid + dbuf 2-phase K-loop.
//      NEW: epilogue dumps scaled tile to LDS [128][132] then does BOTH the
//      direct and mirror G-read/out-write as coalesced float4 (512 B/wave). ----
__global__ void __launch_bounds__(256, 2)
k_final(const bf16* __restrict__ A2, const float* __restrict__ invDV,
        const float* __restrict__ G, float* __restrict__ out){
  __shared__ __align__(16) unsigned char sm[128*132*4];   // 67584 B (>= 2x32768 for K-loop)
  const int t    = threadIdx.x;
  const int lane = t & 63;
  const int w    = t >> 6;
  const int wr   = w >> 1, wc = w & 1;

  // triangular index -> (bi, bj), bj >= bi
  int idx = blockIdx.x;
  int bi = (int)(32.5f - sqrtf(32.5f*32.5f - 2.f*(float)idx));
  while ((bi+1)*32 - ((bi+1)*bi)/2 <= idx) ++bi;
  while (bi*32 - (bi*(bi-1))/2 > idx) --bi;
  int bj = bi + (idx - (bi*32 - (bi*(bi-1))/2));
  const int i0 = bi*128, j0 = bj*128;

  const bf16* PA = A2 + (size_t)i0*NE;
  const bf16* PB = A2 + (size_t)j0*NE;

  f32x4 acc[4][4] = {};
  STAGE128(sm, PA, NE, PB, NE, 0);
  __syncthreads();
  int cur = 0;
  for (int kt = 0; kt < 16; ++kt){
    if (kt < 15) STAGE128(sm + (cur^1)*32768, PA, NE, PB, NE, (kt+1)*64);
    COMPUTE64(sm + cur*32768);
    __syncthreads();
    cur ^= 1;
  }

  float dvi[4][4], dvj[4];
  #pragma unroll
  for (int mi = 0; mi < 4; ++mi)
    #pragma unroll
    for (int q = 0; q < 4; ++q)
      dvi[mi][q] = invDV[i0 + wr*64 + mi*16 + (lane>>4)*4 + q];
  #pragma unroll
  for (int ni = 0; ni < 4; ++ni)
    dvj[ni] = invDV[j0 + wc*64 + ni*16 + (lane & 15)];

  // scaled tile -> LDS  (2-way bank aliasing only; free)
  float (*T)[132] = (float(*)[132])sm;
  #pragma unroll
  for (int mi = 0; mi < 4; ++mi)
    #pragma unroll
    for (int ni = 0; ni < 4; ++ni)
      #pragma unroll
      for (int q = 0; q < 4; ++q)
        T[wr*64 + mi*16 + (lane>>4)*4 + q][wc*64 + ni*16 + (lane & 15)] =
          0.01f*(dvi[mi][q]*dvj[ni]*acc[mi][ni][q]);
  __syncthreads();

  // direct tile: float4 over columns
  #pragma unroll
  for (int it = 0; it < 16; ++it){
    int idx2 = it*256 + t;
    int il = idx2 >> 5;
    int jc = (idx2 & 31)*4;
    size_t o = (size_t)(i0+il)*NN + j0 + jc;
    float4 gv = *(const float4*)(G + o);
    float4 r;
    r.x = 0.99f*gv.x + T[il][jc+0];
    r.y = 0.99f*gv.y + T[il][jc+1];
    r.z = 0.99f*gv.z + T[il][jc+2];
    r.w = 0.99f*gv.w + T[il][jc+3];
    *(float4*)(out + o) = r;
  }

  if (bi == bj) return;
  // mirror tile: transpose read from LDS, float4 write
  #pragma unroll
  for (int it = 0; it < 16; ++it){
    int idx2 = it*256 + t;
    int jl = idx2 >> 5;
    int ic = (idx2 & 31)*4;
    size_t o = (size_t)(j0+jl)*NN + i0 + ic;
    float4 gv = *(const float4*)(G + o);
    float4 r;
    r.x = 0.99f*gv.x + T[ic+0][jl];
    r.y = 0.99f*gv.y + T[ic+1][jl];
    r.z = 0.99f*gv.z + T[ic+2][jl];
    r.w = 0.99f*gv.w + T[ic+3][jl];
    *(float4*)(out + o) = r;
  }
}

extern "C" void kernel_launch(void* const* d_in, const int* in_sizes, int n_in,
                              void* d_out, int out_size, void* d_ws, size_t ws_size,
                              hipStream_t stream){
  const float* adj  = (const float*)d_in[0];
  const float* G    = (const float*)d_in[1];
  const float* feats= (const float*)d_in[2];
  const float* Wv   = (const float*)d_in[3];
  const float* lin  = (const float*)d_in[4];
  const float* wow  = (const float*)d_in[5];
  const float* wob  = (const float*)d_in[6];
  const float* ln1w = (const float*)d_in[7];
  const float* ln1b = (const float*)d_in[8];
  const float* ln2w = (const float*)d_in[9];
  const float* ln2b = (const float*)d_in[10];
  float* out = (float*)d_out;

  float* w = (float*)d_ws;
  float* colsum = w; w += NE;
  float* DE     = w; w += NE;   // becomes rsqrt(DE) in place
  float* sq_s   = w; w += NE;
  float* rowsum = w; w += NN;
  float* sq_d   = w; w += NN;
  float* invDV  = w; w += NN;
  float* ecT    = w; w += NE*DIN;
  float* f      = w; w += NN*HD;
  float* dpre   = w; w += NN*HD;
  unsigned short* swb    = (unsigned short*)w; w += NE*HD/2;   // bf16 s*w_o
  unsigned short* dmatb  = (unsigned short*)w; w += NN*HD/2;   // bf16 d
  unsigned short* fbm    = (unsigned short*)w; w += NN*HD/2;   // bf16 f
  unsigned short* fbT    = (unsigned short*)w; w += NN*HD/2;   // bf16 f^T
  unsigned short* featsT = (unsigned short*)w; w += NN*DIN/2;  // bf16 feats^T (256 x 4096)
  bf16*  Hm     = (bf16*)w;     // NN*NE bf16 = 8 MB
  unsigned short* adjT = (unsigned short*)Hm;  // bf16 adj^T (1024 x 4096) -- aliases Hm:
                                               // dead before k_hm writes Hm (stream-ordered)

  hipMemsetAsync(colsum, 0, NE*sizeof(float), stream);
  hipMemsetAsync(DE,     0, NE*sizeof(float), stream);
  hipMemsetAsync(rowsum, 0, NN*sizeof(float), stream);
  hipMemsetAsync(ecT,    0, (size_t)NE*DIN*sizeof(float), stream);
  hipMemsetAsync(f,      0, (size_t)NN*HD*sizeof(float), stream);
  hipMemsetAsync(dpre,   0, (size_t)NN*HD*sizeof(float), stream);

  k_t2b     <<<dim3(64,4),   256, 0, stream>>>(feats, featsT, nullptr);
  k_t2b     <<<dim3(64,16),  256, 0, stream>>>(adj, adjT, colsum);
  k_ect_mfma<<<dim3(2,8,16), 256, 0, stream>>>(featsT, adjT, ecT);
  k_s       <<<NE,            64, 0, stream>>>(ecT, colsum, lin, ln1w, ln1b, wow, swb, sq_s);
  k_f       <<<dim3(64,4),   256, 0, stream>>>(feats, Wv, f);
  k_f2b     <<<64,           256, 0, stream>>>(f, fbm, fbT);
  k_attn    <<<dim3(64,16),  256, 0, stream>>>(fbm, fbT, dpre, rowsum);
  k_dln     <<<NN/4,         256, 0, stream>>>(dpre, rowsum, ln2w, ln2b, wow, dmatb, sq_d);
  k_hm      <<<dim3(64,16),  256, 0, stream>>>(dmatb, swb, sq_d, sq_s, wob, Hm);
  k_dv      <<<NN,           256, 0, stream>>>(Hm, invDV);
  k_de      <<<dim3(4,32),   256, 0, stream>>>(Hm, DE);
  k_invde   <<<4,            256, 0, stream>>>(DE);
  k_scale   <<<2048,         256, 0, stream>>>(Hm, DE);
  k_final   <<<528,          256, 0, stream>>>(Hm, invDV, G, out);
}

// Round 5
// 339.692 us; speedup vs baseline: 3.1088x; 1.0057x over previous
//
#include <hip/hip_runtime.h>
#include <hip/hip_bf16.h>
#include <math.h>

#define NN 4096
#define NE 1024
#define DIN 256
#define HD 64

typedef __hip_bfloat16 bf16;
__device__ __forceinline__ float b2f(bf16 x){ return __bfloat162float(x); }

typedef __attribute__((ext_vector_type(8))) short s16x8;   // 8 bf16 = 4 VGPR
typedef __attribute__((ext_vector_type(4))) float f32x4;   // MFMA 16x16 acc

__device__ __forceinline__ unsigned short f2b_rne(float x){  // RNE f32->bf16 (finite)
  unsigned u; __builtin_memcpy(&u, &x, 4);
  u += 0x7fff + ((u>>16)&1);
  return (unsigned short)(u>>16);
}

// Stage 128 rows x 64 k (2B elems) of A and B into LDS (linear dest, inverse-swizzled src).
#define STAGE128(dstbase, PA, strideA, PB, strideB, k0) do{ \
  _Pragma("unroll") \
  for (int it_ = 0; it_ < 4; ++it_){ \
    int r_  = it_*32 + (t>>3); \
    int ss_ = ((t&7) ^ (r_&7))*8; \
    __builtin_amdgcn_global_load_lds( \
      (const __attribute__((address_space(1))) void*)((PA) + (size_t)r_*(strideA) + (k0) + ss_), \
      (__attribute__((address_space(3))) void*)((dstbase) + it_*4096 + t*16), 16, 0, 0); \
    __builtin_amdgcn_global_load_lds( \
      (const __attribute__((address_space(1))) void*)((PB) + (size_t)r_*(strideB) + (k0) + ss_), \
      (__attribute__((address_space(3))) void*)((dstbase) + 16384 + it_*4096 + t*16), 16, 0, 0); \
  } }while(0)

// One BK=64 step: 16 ds_read_b128 (swizzled) + 32 MFMA. Uses: wr, wc, lane, acc.
#define COMPUTE64(base) do{ \
  _Pragma("unroll") \
  for (int kk_ = 0; kk_ < 2; ++kk_){ \
    s16x8 a_[4], b_[4]; \
    _Pragma("unroll") \
    for (int mi_ = 0; mi_ < 4; ++mi_){ \
      int row_ = wr*64 + mi_*16 + (lane & 15); \
      int s_   = kk_*4 + (lane >> 4); \
      a_[mi_] = *(const s16x8*)((base) + row_*128 + ((s_ ^ (row_&7))*16)); \
    } \
    _Pragma("unroll") \
    for (int ni_ = 0; ni_ < 4; ++ni_){ \
      int row_ = wc*64 + ni_*16 + (lane & 15); \
      int s_   = kk_*4 + (lane >> 4); \
      b_[ni_] = *(const s16x8*)((base) + 16384 + row_*128 + ((s_ ^ (row_&7))*16)); \
    } \
    _Pragma("unroll") \
    for (int mi_ = 0; mi_ < 4; ++mi_) \
      _Pragma("unroll") \
      for (int ni_ = 0; ni_ < 4; ++ni_) \
        acc[mi_][ni_] = __builtin_amdgcn_mfma_f32_16x16x32_bf16(a_[mi_], b_[ni_], acc[mi_][ni_], 0, 0, 0); \
  } }while(0)

// ---- 1. transpose f32 -> bf16: dst[c][r] = bf16(src[r][c]); optional col-sum of src. ----
__global__ void k_t2b(const float* __restrict__ src, unsigned short* __restrict__ dst,
                      float* __restrict__ csum){
  __shared__ float Ls[64][65];
  int R = gridDim.x*64, C = gridDim.y*64;
  int r0 = blockIdx.x*64, c0 = blockIdx.y*64;
  int t = threadIdx.x;
  int lr = t>>2, lc = (t&3)*16;
  #pragma unroll
  for (int s = 0; s < 4; ++s){
    float4 v = *(const float4*)(src + (size_t)(r0+lr)*C + c0 + lc + s*4);
    Ls[lr][lc+s*4+0]=v.x; Ls[lr][lc+s*4+1]=v.y; Ls[lr][lc+s*4+2]=v.z; Ls[lr][lc+s*4+3]=v.w;
  }
  __syncthreads();
  if (csum != nullptr && t < 64){
    float s = 0.f;
    #pragma unroll
    for (int r = 0; r < 64; ++r) s += Ls[r][t];
    atomicAdd(&csum[c0 + t], s);
  }
  int wc = t>>3, wr8 = (t&7)*8;
  #pragma unroll
  for (int p = 0; p < 2; ++p){
    int c = wc + p*32;
    s16x8 o;
    #pragma unroll
    for (int e = 0; e < 8; ++e) o[e] = (short)f2b_rne(Ls[wr8+e][c]);
    *(s16x8*)(dst + (size_t)(c0+c)*R + r0 + wr8) = o;
  }
}

// ---- 2. ecT[e][c] += sum_i feats[i][c]*adj[i][e] -- bf16 MFMA, K-chunked (atomics). ----
__global__ void __launch_bounds__(256, 2)
k_ect_mfma(const unsigned short* __restrict__ fT, const unsigned short* __restrict__ aT,
           float* __restrict__ ecT){
  __shared__ __align__(16) unsigned char sm[65536];
  const int t = threadIdx.x, lane = t & 63, w = t >> 6;
  const int wr = w >> 1, wc = w & 1;
  const int m0 = blockIdx.x*128, n0 = blockIdx.y*128, kb = blockIdx.z*256;
  const unsigned short* PA = fT + (size_t)m0*NN + kb;
  const unsigned short* PB = aT + (size_t)n0*NN + kb;
  f32x4 acc[4][4] = {};
  STAGE128(sm, PA, NN, PB, NN, 0);
  __syncthreads();
  int cur = 0;
  for (int kt = 0; kt < 4; ++kt){
    if (kt < 3) STAGE128(sm + (cur^1)*32768, PA, NN, PB, NN, (kt+1)*64);
    COMPUTE64(sm + cur*32768);
    __syncthreads();
    cur ^= 1;
  }
  #pragma unroll
  for (int mi = 0; mi < 4; ++mi)
    #pragma unroll
    for (int q = 0; q < 4; ++q){
      int c = m0 + wr*64 + mi*16 + (lane>>4)*4 + q;
      #pragma unroll
      for (int ni = 0; ni < 4; ++ni){
        int e = n0 + wc*64 + ni*16 + (lane & 15);
        atomicAdd(&ecT[(size_t)e*DIN + c], acc[mi][ni][q]);
      }
    }
}

// ---- 3. s = LN1((ecT/colsum) @ lin_w^T); swb = bf16(s*w_o), sq_s = sum_h w*s^2 ----
__global__ void k_s(const float* __restrict__ ecT, const float* __restrict__ colsum,
                    const float* __restrict__ lin_w,
                    const float* __restrict__ ln1w, const float* __restrict__ ln1b,
                    const float* __restrict__ wow,
                    unsigned short* __restrict__ swb, float* __restrict__ sq_s){
  int e = blockIdx.x, h = threadIdx.x;
  const float* row = ecT + (size_t)e*DIN;
  const float* lw  = lin_w + (size_t)h*DIN;
  float acc = 0.f;
  for (int c = 0; c < DIN; ++c) acc += row[c]*lw[c];
  acc /= colsum[e];
  float tot = acc;
  for (int m=32;m>=1;m>>=1) tot += __shfl_xor(tot,m);
  float mean = tot*(1.f/64.f);
  float dv = acc - mean;
  float vv = dv*dv;
  for (int m=32;m>=1;m>>=1) vv += __shfl_xor(vv,m);
  float y = dv*(1.f/sqrtf(vv*(1.f/64.f)+1e-5f))*ln1w[h] + ln1b[h];
  float wv = wow[h];
  swb[(size_t)e*HD + h] = f2b_rne(y*wv);
  float q = wv*y*y;
  for (int m=32;m>=1;m>>=1) q += __shfl_xor(q,m);
  if (h==0) sq_s[e] = q;
}

// ---- 4. f = feats @ W_v^T (full K in-block, no atomics); writes fb + fbT (bf16). ----
__global__ void k_f_full(const float* __restrict__ feats, const float* __restrict__ Wv,
                         unsigned short* __restrict__ fb, unsigned short* __restrict__ fbT){
  __shared__ float As[64][65]; // [k(c)][m(i)]
  __shared__ float Bs[64][65]; // [k(c)][n(h)]
  __shared__ unsigned short Fs[64][72];
  int i0 = blockIdx.x*64;
  int tid=threadIdx.x, tx=tid&15, ty=tid>>4;
  float acc[4][4]={};
  for (int c0=0;c0<DIN;c0+=64){
    if (c0) __syncthreads();
    for (int idx=tid; idx<4096; idx+=256){
      int r=idx>>6, c=idx&63;
      As[c][r] = feats[(size_t)(i0+r)*DIN + c0+c];
      Bs[c][r] = Wv   [(size_t)r*DIN      + c0+c];
    }
    __syncthreads();
    for (int k=0;k<64;++k){
      float a[4], b[4];
      #pragma unroll
      for (int i=0;i<4;++i) a[i] = As[k][tx*4+i];
      #pragma unroll
      for (int i=0;i<4;++i) b[i] = Bs[k][ty*4+i];
      #pragma unroll
      for (int mi=0;mi<4;++mi)
        #pragma unroll
        for (int ni=0;ni<4;++ni) acc[mi][ni] += a[mi]*b[ni];
    }
  }
  #pragma unroll
  for (int mi=0;mi<4;++mi)
    #pragma unroll
    for (int ni=0;ni<4;++ni)
      Fs[tx*4+mi][ty*4+ni] = f2b_rne(acc[mi][ni]);
  __syncthreads();
  {
    int r = tid>>2, c0b = (tid&3)*16;
    s16x8 v0, v1;
    #pragma unroll
    for (int e=0;e<8;++e){ v0[e] = (short)Fs[r][c0b+e]; v1[e] = (short)Fs[r][c0b+8+e]; }
    *(s16x8*)(fb + (size_t)(i0+r)*HD + c0b)     = v0;
    *(s16x8*)(fb + (size_t)(i0+r)*HD + c0b + 8) = v1;
  }
  {
    int h = tid>>2, n1 = (tid&3)*16;
    s16x8 w0, w1;
    #pragma unroll
    for (int e=0;e<8;++e){ w0[e] = (short)Fs[n1+e][h]; w1[e] = (short)Fs[n1+8+e][h]; }
    *(s16x8*)(fbT + (size_t)h*NN + i0 + n1)     = w0;
    *(s16x8*)(fbT + (size_t)h*NN + i0 + n1 + 8) = w1;
  }
}

// ---- 5+6 fused MFMA attention (S, exp, rowsum, PV). Double-buffered prefetch:
//      stage jt+1 before compute jt; ONE barrier per tile. LDS 48 KB. ----
#define STAGE_ATTN(buf, j0s) do{ \
  _Pragma("unroll") \
  for (int p_=0;p_<2;++p_){ \
    int r_  = p_*32 + (t>>3); \
    int cs_ = ((t&7) ^ (r_&7))*8; \
    __builtin_amdgcn_global_load_lds( \
      (const __attribute__((address_space(1))) void*)(fb + (size_t)((j0s)+r_)*HD + cs_), \
      (__attribute__((address_space(3))) void*)(sm + (buf)*16384 + p_*4096 + t*16), 16, 0, 0); \
    __builtin_amdgcn_global_load_lds( \
      (const __attribute__((address_space(1))) void*)(fbT + (size_t)r_*NN + (j0s) + cs_), \
      (__attribute__((address_space(3))) void*)(sm + (buf)*16384 + 8192 + p_*4096 + t*16), 16, 0, 0); \
  } }while(0)

__global__ void __launch_bounds__(256)
k_attn(const unsigned short* __restrict__ fb, const unsigned short* __restrict__ fbT,
       float* __restrict__ dpre, float* __restrict__ rowsum){
  __shared__ __align__(16) unsigned char sm[49152];
  const int t  = threadIdx.x;
  const int l  = t & 63;
  const int w  = t >> 6;
  const int g  = l >> 4;
  const int i0 = blockIdx.x*64;
  const int jb0 = blockIdx.y*256;

  s16x8 aQ[2];
  {
    const unsigned short* src = fb + (size_t)(i0 + w*16 + (l&15))*HD + g*8;
    aQ[0] = *(const s16x8*)(src);
    aQ[1] = *(const s16x8*)(src + 32);
  }

  f32x4 acco[4];
  #pragma unroll
  for (int nh=0;nh<4;++nh)
    #pragma unroll
    for (int q=0;q<4;++q) acco[nh][q] = 0.f;
  float rsum[4] = {0.f,0.f,0.f,0.f};

  float* Pw = (float*)(sm + 32768 + w*4096);   // wave-private [16][64] f32, swizzled

  STAGE_ATTN(0, jb0);
  __syncthreads();
  int cur = 0;
  for (int jt = 0; jt < 4; ++jt){
    if (jt < 3) STAGE_ATTN(cur^1, jb0 + (jt+1)*64);
    const unsigned char* B = sm + cur*16384;

    f32x4 accs[4];
    #pragma unroll
    for (int nj=0;nj<4;++nj)
      #pragma unroll
      for (int q=0;q<4;++q) accs[nj][q] = 0.f;
    #pragma unroll
    for (int kk=0; kk<2; ++kk){
      int s = kk*4 + g;
      #pragma unroll
      for (int nj=0;nj<4;++nj){
        int row = nj*16 + (l&15);
        s16x8 b = *(const s16x8*)(B + row*128 + ((s ^ (row&7))*16));
        accs[nj] = __builtin_amdgcn_mfma_f32_16x16x32_bf16(aQ[kk], b, accs[nj], 0,0,0);
      }
    }

    #pragma unroll
    for (int q=0;q<4;++q){
      int i  = g*4 + q;
      int sw = (i&7)<<2;
      #pragma unroll
      for (int nj=0;nj<4;++nj){
        float p = __expf(accs[nj][q]*0.125f);
        rsum[q] += p;
        Pw[i*64 + ((nj*16 + (l&15)) ^ sw)] = p;
      }
    }

    #pragma unroll
    for (int kk=0; kk<2; ++kk){
      int i  = l & 15;
      int sw = (i&7)<<2;
      int jb = g*8 + kk*32;
      f32x4 va = *(const f32x4*)(Pw + i*64 + ( jb      ^ sw));
      f32x4 vb = *(const f32x4*)(Pw + i*64 + ((jb + 4) ^ sw));
      s16x8 pa;
      #pragma unroll
      for (int e=0;e<4;++e){
        float fa = va[e], fbv = vb[e];
        pa[e]   = (short)f2b_rne(fa);
        pa[4+e] = (short)f2b_rne(fbv);
      }
      int s = kk*4 + g;
      #pragma unroll
      for (int nh=0;nh<4;++nh){
        int row = nh*16 + (l&15);
        s16x8 bT = *(const s16x8*)(B + 8192 + row*128 + ((s ^ (row&7))*16));
        acco[nh] = __builtin_amdgcn_mfma_f32_16x16x32_bf16(pa, bT, acco[nh], 0,0,0);
      }
    }
    __syncthreads();   // drains vmcnt (next tile staged) + protects buffer reuse
    cur ^= 1;
  }

  #pragma unroll
  for (int q=0;q<4;++q){
    float v = rsum[q];
    v += __shfl_xor(v,1); v += __shfl_xor(v,2);
    v += __shfl_xor(v,4); v += __shfl_xor(v,8);
    if ((l&15)==0) atomicAdd(&rowsum[i0 + w*16 + g*4 + q], v);
  }
  #pragma unroll
  for (int nh=0;nh<4;++nh)
    #pragma unroll
    for (int q=0;q<4;++q)
      atomicAdd(&dpre[(size_t)(i0 + w*16 + g*4 + q)*HD + nh*16 + (l&15)], acco[nh][q]);
}

// ---- 7. d = LN2(dpre/rowsum); dmatb (bf16), sq_d ----
__global__ void k_dln(const float* __restrict__ dpre, const float* __restrict__ rowsum,
                      const float* __restrict__ ln2w, const float* __restrict__ ln2b,
                      const float* __restrict__ wow,
                      unsigned short* __restrict__ dmatb, float* __restrict__ sq_d){
  int lane = threadIdx.x & 63;
  int n = blockIdx.x*4 + (threadIdx.x>>6);
  float x = dpre[(size_t)n*HD + lane] / rowsum[n];
  float tot = x;
  for (int m=32;m>=1;m>>=1) tot += __shfl_xor(tot,m);
  float mean = tot*(1.f/64.f);
  float dv = x - mean;
  float vv = dv*dv;
  for (int m=32;m>=1;m>>=1) vv += __shfl_xor(vv,m);
  float y = dv*(1.f/sqrtf(vv*(1.f/64.f)+1e-5f))*ln2w[lane] + ln2b[lane];
  dmatb[(size_t)n*HD + lane] = f2b_rne(y);
  float wv = wow[lane];
  float q = wv*y*y;
  for (int m=32;m>=1;m>>=1) q += __shfl_xor(q,m);
  if (lane==0) sq_d[n] = q;
}

// ---- 8. Hm[n][e] = exp(-(sq_s[e]+sq_d[n]-2*dot(sw[e],d[n])+b)/800) -- MFMA.
//      NEW: also emits row-sum partials (DVacc) and col-sum partials (DE) of the
//      STORED bf16 values -> k_dv/k_de/k_invde deleted. ----
__global__ void __launch_bounds__(256)
k_hm(const unsigned short* __restrict__ dmatb, const unsigned short* __restrict__ swb,
     const float* __restrict__ sq_d, const float* __restrict__ sq_s,
     const float* __restrict__ wob, bf16* __restrict__ Hm,
     float* __restrict__ DE, float* __restrict__ DVacc){
  __shared__ __align__(16) unsigned char sm[8192];
  __shared__ float DEp[64];
  const int t = threadIdx.x, l = t & 63, w = t >> 6, g = l >> 4;
  const int n0 = blockIdx.x*64, e0 = blockIdx.y*64;
  #pragma unroll
  for (int p = 0; p < 2; ++p){
    int r  = p*32 + (t>>3);
    int cs = ((t&7) ^ (r&7))*8;
    __builtin_amdgcn_global_load_lds(
      (const __attribute__((address_space(1))) void*)(swb + (size_t)(e0+r)*HD + cs),
      (__attribute__((address_space(3))) void*)(sm + p*4096 + t*16), 16, 0, 0);
  }
  s16x8 aQ[2];
  {
    const unsigned short* src = dmatb + (size_t)(n0 + w*16 + (l&15))*HD + g*8;
    aQ[0] = *(const s16x8*)(src);
    aQ[1] = *(const s16x8*)(src + 32);
  }
  if (t < 64) DEp[t] = 0.f;
  f32x4 accs[4];
  #pragma unroll
  for (int nj=0;nj<4;++nj)
    #pragma unroll
    for (int q=0;q<4;++q) accs[nj][q] = 0.f;
  __syncthreads();
  #pragma unroll
  for (int kk=0; kk<2; ++kk){
    int s = kk*4 + g;
    #pragma unroll
    for (int nj=0;nj<4;++nj){
      int row = nj*16 + (l&15);
      s16x8 b = *(const s16x8*)(sm + row*128 + ((s ^ (row&7))*16));
      accs[nj] = __builtin_amdgcn_mfma_f32_16x16x32_bf16(aQ[kk], b, accs[nj], 0,0,0);
    }
  }
  float bias = wob[0];
  float sqd[4];
  #pragma unroll
  for (int q=0;q<4;++q) sqd[q] = sq_d[n0 + w*16 + g*4 + q];
  float rowp[4] = {0.f,0.f,0.f,0.f};
  #pragma unroll
  for (int nj=0;nj<4;++nj){
    int e = e0 + nj*16 + (l&15);
    float sqs = sq_s[e];
    float colp = 0.f;
    #pragma unroll
    for (int q=0;q<4;++q){
      float ta = sqs + sqd[q] - 2.f*accs[nj][q] + bias;
      float arg = -ta*(1.f/800.f);
      if (!(arg > -88.f)) arg = -88.f;
      if (arg > 60.f)     arg = 60.f;
      int n = n0 + w*16 + g*4 + q;
      bf16 hv = __float2bfloat16(__expf(arg));
      Hm[(size_t)n*NE + e] = hv;
      float vr = b2f(hv);
      rowp[q] += vr;
      colp    += vr;
    }
    atomicAdd(&DEp[nj*16 + (l&15)], colp);
  }
  #pragma unroll
  for (int q=0;q<4;++q){
    float v = rowp[q];
    v += __shfl_xor(v,1); v += __shfl_xor(v,2);
    v += __shfl_xor(v,4); v += __shfl_xor(v,8);
    if ((l&15)==0) atomicAdd(&DVacc[n0 + w*16 + g*4 + q], v);
  }
  __syncthreads();
  if (t < 64) atomicAdd(&DE[e0 + t], DEp[t]);
}

// ---- 10b. In-place: A2[n][e] = Hm[n][e] * rsqrt(DE[e])  (rsqrt inline) ----
__global__ void k_scale(bf16* __restrict__ Hm, const float* __restrict__ DE){
  int idx = blockIdx.x*256 + threadIdx.x;
  int row = idx >> 7, c8 = idx & 127;
  size_t base = (size_t)row*NE + c8*8;
  s16x8 v = *(const s16x8*)(Hm + base);
  s16x8 o;
  #pragma unroll
  for (int j = 0; j < 8; ++j){
    float de = DE[c8*8 + j];
    float r  = (de > 0.f) ? rsqrtf(de) : 0.f;
    unsigned int ww = ((unsigned int)(unsigned short)v[j]) << 16;
    float fv; __builtin_memcpy(&fv, &ww, 4);
    fv *= r;
    o[j] = (short)f2b_rne(fv);
  }
  *(s16x8*)(Hm + base) = o;
}

// ---- 11. out = 0.99*G + 0.01*invDV_i*invDV_j*(A2 @ A2^T).
//      Compact tri-grid (XCD-swizzled) + dbuf K-loop.
//      Epilogue: row-major T dump -> coalesced direct pass; then TRANSPOSED
//      re-dump -> coalesced conflict-free mirror pass. ----
__global__ void __launch_bounds__(256, 2)
k_final(const bf16* __restrict__ A2, const float* __restrict__ DVacc,
        const float* __restrict__ G, float* __restrict__ out){
  __shared__ __align__(16) unsigned char sm[128*132*4];   // 67584 B (>= 2x32768 for K-loop)
  const int t    = threadIdx.x;
  const int lane = t & 63;
  const int w    = t >> 6;
  const int wr   = w >> 1, wc = w & 1;

  // XCD-aware swizzle of the 528-block tri-grid (528 = 8*66, bijective)
  int bid = blockIdx.x;
  int idx = (bid & 7)*66 + (bid >> 3);
  // triangular index -> (bi, bj), bj >= bi
  int bi = (int)(32.5f - sqrtf(32.5f*32.5f - 2.f*(float)idx));
  while ((bi+1)*32 - ((bi+1)*bi)/2 <= idx) ++bi;
  while (bi*32 - (bi*(bi-1))/2 > idx) --bi;
  int bj = bi + (idx - (bi*32 - (bi*(bi-1))/2));
  const int i0 = bi*128, j0 = bj*128;

  const bf16* PA = A2 + (size_t)i0*NE;
  const bf16* PB = A2 + (size_t)j0*NE;

  f32x4 acc[4][4] = {};
  STAGE128(sm, PA, NE, PB, NE, 0);
  __syncthreads();
  int cur = 0;
  for (int kt = 0; kt < 16; ++kt){
    if (kt < 15) STAGE128(sm + (cur^1)*32768, PA, NE, PB, NE, (kt+1)*64);
    COMPUTE64(sm + cur*32768);
    __syncthreads();
    cur ^= 1;
  }

  float dvi[4][4], dvj[4];
  #pragma unroll
  for (int mi = 0; mi < 4; ++mi)
    #pragma unroll
    for (int q = 0; q < 4; ++q){
      float v = DVacc[i0 + wr*64 + mi*16 + (lane>>4)*4 + q];
      dvi[mi][q] = (v > 0.f) ? rsqrtf(v) : 0.f;
    }
  #pragma unroll
  for (int ni = 0; ni < 4; ++ni){
    float v = DVacc[j0 + wc*64 + ni*16 + (lane & 15)];
    dvj[ni] = (v > 0.f) ? rsqrtf(v) : 0.f;
  }

  // scaled tile -> LDS row-major
  float (*T)[132] = (float(*)[132])sm;
  #pragma unroll
  for (int mi = 0; mi < 4; ++mi)
    #pragma unroll
    for (int ni = 0; ni < 4; ++ni)
      #pragma unroll
      for (int q = 0; q < 4; ++q)
        T[wr*64 + mi*16 + (lane>>4)*4 + q][wc*64 + ni*16 + (lane & 15)] =
          0.01f*(dvi[mi][q]*dvj[ni]*acc[mi][ni][q]);
  __syncthreads();

  // direct tile: float4 over columns (conflict-free row reads)
  #pragma unroll
  for (int it = 0; it < 16; ++it){
    int idx2 = it*256 + t;
    int il = idx2 >> 5;
    int jc = (idx2 & 31)*4;
    size_t o = (size_t)(i0+il)*NN + j0 + jc;
    float4 gv = *(const float4*)(G + o);
    float4 r;
    r.x = 0.99f*gv.x + T[il][jc+0];
    r.y = 0.99f*gv.y + T[il][jc+1];
    r.z = 0.99f*gv.z + T[il][jc+2];
    r.w = 0.99f*gv.w + T[il][jc+3];
    *(float4*)(out + o) = r;
  }

  if (bi == bj) return;
  __syncthreads();            // all direct reads of T done
  // re-dump TRANSPOSED: Tt[j_local][i_local]
  #pragma unroll
  for (int mi = 0; mi < 4; ++mi)
    #pragma unroll
    for (int ni = 0; ni < 4; ++ni)
      #pragma unroll
      for (int q = 0; q < 4; ++q)
        T[wc*64 + ni*16 + (lane & 15)][wr*64 + mi*16 + (lane>>4)*4 + q] =
          0.01f*(dvi[mi][q]*dvj[ni]*acc[mi][ni][q]);
  __syncthreads();
  // mirror tile: row-major float4 reads of Tt (conflict-free)
  #pragma unroll
  for (int it = 0; it < 16; ++it){
    int idx2 = it*256 + t;
    int jl = idx2 >> 5;
    int ic = (idx2 & 31)*4;
    size_t o = (size_t)(j0+jl)*NN + i0 + ic;
    float4 gv = *(const float4*)(G + o);
    float4 r;
    r.x = 0.99f*gv.x + T[jl][ic+0];
    r.y = 0.99f*gv.y + T[jl][ic+1];
    r.z = 0.99f*gv.z + T[jl][ic+2];
    r.w = 0.99f*gv.w + T[jl][ic+3];
    *(float4*)(out + o) = r;
  }
}

extern "C" void kernel_launch(void* const* d_in, const int* in_sizes, int n_in,
                              void* d_out, int out_size, void* d_ws, size_t ws_size,
                              hipStream_t stream){
  const float* adj  = (const float*)d_in[0];
  const float* G    = (const float*)d_in[1];
  const float* feats= (const float*)d_in[2];
  const float* Wv   = (const float*)d_in[3];
  const float* lin  = (const float*)d_in[4];
  const float* wow  = (const float*)d_in[5];
  const float* wob  = (const float*)d_in[6];
  const float* ln1w = (const float*)d_in[7];
  const float* ln1b = (const float*)d_in[8];
  const float* ln2w = (const float*)d_in[9];
  const float* ln2b = (const float*)d_in[10];
  float* out = (float*)d_out;

  float* w = (float*)d_ws;
  float* colsum = w; w += NE;
  float* DE     = w; w += NE;   // raw col sums; rsqrt folded into k_scale
  float* sq_s   = w; w += NE;
  float* rowsum = w; w += NN;
  float* sq_d   = w; w += NN;
  float* DVacc  = w; w += NN;   // raw row sums; rsqrt folded into k_final
  float* ecT    = w; w += NE*DIN;
  float* dpre   = w; w += NN*HD;
  unsigned short* swb    = (unsigned short*)w; w += NE*HD/2;   // bf16 s*w_o
  unsigned short* dmatb  = (unsigned short*)w; w += NN*HD/2;   // bf16 d
  unsigned short* fbm    = (unsigned short*)w; w += NN*HD/2;   // bf16 f
  unsigned short* fbT    = (unsigned short*)w; w += NN*HD/2;   // bf16 f^T
  unsigned short* featsT = (unsigned short*)w; w += NN*DIN/2;  // bf16 feats^T (256 x 4096)
  bf16*  Hm     = (bf16*)w;     // NN*NE bf16 = 8 MB
  unsigned short* adjT = (unsigned short*)Hm;  // bf16 adj^T aliases Hm (dead before k_hm)

  hipMemsetAsync(colsum, 0, NE*sizeof(float), stream);
  hipMemsetAsync(DE,     0, NE*sizeof(float), stream);
  hipMemsetAsync(rowsum, 0, NN*sizeof(float), stream);
  hipMemsetAsync(DVacc,  0, NN*sizeof(float), stream);
  hipMemsetAsync(ecT,    0, (size_t)NE*DIN*sizeof(float), stream);
  hipMemsetAsync(dpre,   0, (size_t)NN*HD*sizeof(float), stream);

  k_t2b     <<<dim3(64,4),   256, 0, stream>>>(feats, featsT, nullptr);
  k_t2b     <<<dim3(64,16),  256, 0, stream>>>(adj, adjT, colsum);
  k_ect_mfma<<<dim3(2,8,16), 256, 0, stream>>>(featsT, adjT, ecT);
  k_s       <<<NE,            64, 0, stream>>>(ecT, colsum, lin, ln1w, ln1b, wow, swb, sq_s);
  k_f_full  <<<64,           256, 0, stream>>>(feats, Wv, fbm, fbT);
  k_attn    <<<dim3(64,16),  256, 0, stream>>>(fbm, fbT, dpre, rowsum);
  k_dln     <<<NN/4,         256, 0, stream>>>(dpre, rowsum, ln2w, ln2b, wow, dmatb, sq_d);
  k_hm      <<<dim3(64,16),  256, 0, stream>>>(dmatb, swb, sq_d, sq_s, wob, Hm, DE, DVacc);
  k_scale   <<<2048,         256, 0, stream>>>(Hm, DE);
  k_final   <<<528,          256, 0, stream>>>(Hm, DVacc, G, out);
}

// Round 6
// 338.791 us; speedup vs baseline: 3.1170x; 1.0027x over previous
//
#include <hip/hip_runtime.h>
#include <hip/hip_bf16.h>
#include <math.h>

#define NN 4096
#define NE 1024
#define DIN 256
#define HD 64

typedef __hip_bfloat16 bf16;
__device__ __forceinline__ float b2f(bf16 x){ return __bfloat162float(x); }

typedef __attribute__((ext_vector_type(8))) short s16x8;   // 8 bf16 = 4 VGPR
typedef __attribute__((ext_vector_type(4))) float f32x4;   // MFMA 16x16 acc

__device__ __forceinline__ unsigned short f2b_rne(float x){  // RNE f32->bf16 (finite)
  unsigned u; __builtin_memcpy(&u, &x, 4);
  u += 0x7fff + ((u>>16)&1);
  return (unsigned short)(u>>16);
}

// Stage 128 rows x 64 k (2B elems) of A and B into LDS (linear dest, inverse-swizzled src).
#define STAGE128(dstbase, PA, strideA, PB, strideB, k0) do{ \
  _Pragma("unroll") \
  for (int it_ = 0; it_ < 4; ++it_){ \
    int r_  = it_*32 + (t>>3); \
    int ss_ = ((t&7) ^ (r_&7))*8; \
    __builtin_amdgcn_global_load_lds( \
      (const __attribute__((address_space(1))) void*)((PA) + (size_t)r_*(strideA) + (k0) + ss_), \
      (__attribute__((address_space(3))) void*)((dstbase) + it_*4096 + t*16), 16, 0, 0); \
    __builtin_amdgcn_global_load_lds( \
      (const __attribute__((address_space(1))) void*)((PB) + (size_t)r_*(strideB) + (k0) + ss_), \
      (__attribute__((address_space(3))) void*)((dstbase) + 16384 + it_*4096 + t*16), 16, 0, 0); \
  } }while(0)

// One BK=64 step: 16 ds_read_b128 (swizzled) + 32 MFMA. Uses: wr, wc, lane, acc.
#define COMPUTE64(base) do{ \
  _Pragma("unroll") \
  for (int kk_ = 0; kk_ < 2; ++kk_){ \
    s16x8 a_[4], b_[4]; \
    _Pragma("unroll") \
    for (int mi_ = 0; mi_ < 4; ++mi_){ \
      int row_ = wr*64 + mi_*16 + (lane & 15); \
      int s_   = kk_*4 + (lane >> 4); \
      a_[mi_] = *(const s16x8*)((base) + row_*128 + ((s_ ^ (row_&7))*16)); \
    } \
    _Pragma("unroll") \
    for (int ni_ = 0; ni_ < 4; ++ni_){ \
      int row_ = wc*64 + ni_*16 + (lane & 15); \
      int s_   = kk_*4 + (lane >> 4); \
      b_[ni_] = *(const s16x8*)((base) + 16384 + row_*128 + ((s_ ^ (row_&7))*16)); \
    } \
    _Pragma("unroll") \
    for (int mi_ = 0; mi_ < 4; ++mi_) \
      _Pragma("unroll") \
      for (int ni_ = 0; ni_ < 4; ++ni_) \
        acc[mi_][ni_] = __builtin_amdgcn_mfma_f32_16x16x32_bf16(a_[mi_], b_[ni_], acc[mi_][ni_], 0, 0, 0); \
  } }while(0)

// ---- 1. k_prep: fused {feats->featsT, adj->adjT(+colsum), f = feats@Wv^T -> fb,fbT}.
//      Role by blockIdx range; the three independent ops fill the machine together. ----
__global__ void __launch_bounds__(256)
k_prep(const float* __restrict__ feats, const float* __restrict__ adj,
       const float* __restrict__ Wv,
       unsigned short* __restrict__ featsT, unsigned short* __restrict__ adjT,
       float* __restrict__ colsum,
       unsigned short* __restrict__ fb, unsigned short* __restrict__ fbT){
  __shared__ __align__(16) unsigned char smp[42496];
  const int b = blockIdx.x, t = threadIdx.x;
  if (b < 1280){
    // ---- transpose f32 -> bf16 role ----
    const float* src; unsigned short* dst; float* csum; int R, C, bx, by;
    if (b < 256){ src=feats; dst=featsT; csum=nullptr; R=NN; C=DIN; bx=b&63;  by=b>>6; }
    else { int bb=b-256; src=adj; dst=adjT; csum=colsum; R=NN; C=NE; bx=bb&63; by=bb>>6; }
    float (*Ls)[65] = (float(*)[65])smp;
    int r0 = bx*64, c0 = by*64;
    int lr = t>>2, lc = (t&3)*16;
    #pragma unroll
    for (int s = 0; s < 4; ++s){
      float4 v = *(const float4*)(src + (size_t)(r0+lr)*C + c0 + lc + s*4);
      Ls[lr][lc+s*4+0]=v.x; Ls[lr][lc+s*4+1]=v.y; Ls[lr][lc+s*4+2]=v.z; Ls[lr][lc+s*4+3]=v.w;
    }
    __syncthreads();
    if (csum != nullptr && t < 64){
      float s = 0.f;
      #pragma unroll
      for (int r = 0; r < 64; ++r) s += Ls[r][t];
      atomicAdd(&csum[c0 + t], s);
    }
    int wcx = t>>3, wr8 = (t&7)*8;
    #pragma unroll
    for (int p = 0; p < 2; ++p){
      int c = wcx + p*32;
      s16x8 o;
      #pragma unroll
      for (int e = 0; e < 8; ++e) o[e] = (short)f2b_rne(Ls[wr8+e][c]);
      *(s16x8*)(dst + (size_t)(c0+c)*R + r0 + wr8) = o;
    }
  } else {
    // ---- f = feats @ Wv^T role (full K in-block); writes fb + fbT ----
    float (*As)[65] = (float(*)[65])smp;
    float (*Bs)[65] = (float(*)[65])(smp + 16640);
    unsigned short (*Fs)[72] = (unsigned short(*)[72])(smp + 33280);
    int i0 = (b-1280)*64;
    int tx = t&15, ty = t>>4;
    float acc[4][4] = {};
    for (int c0 = 0; c0 < DIN; c0 += 64){
      if (c0) __syncthreads();
      for (int idx = t; idx < 4096; idx += 256){
        int r = idx>>6, c = idx&63;
        As[c][r] = feats[(size_t)(i0+r)*DIN + c0+c];
        Bs[c][r] = Wv   [(size_t)r*DIN      + c0+c];
      }
      __syncthreads();
      for (int k = 0; k < 64; ++k){
        float a[4], bb[4];
        #pragma unroll
        for (int i=0;i<4;++i) a[i]  = As[k][tx*4+i];
        #pragma unroll
        for (int i=0;i<4;++i) bb[i] = Bs[k][ty*4+i];
        #pragma unroll
        for (int mi=0;mi<4;++mi)
          #pragma unroll
          for (int ni=0;ni<4;++ni) acc[mi][ni] += a[mi]*bb[ni];
      }
    }
    #pragma unroll
    for (int mi=0;mi<4;++mi)
      #pragma unroll
      for (int ni=0;ni<4;++ni)
        Fs[tx*4+mi][ty*4+ni] = f2b_rne(acc[mi][ni]);
    __syncthreads();
    {
      int r = t>>2, c0b = (t&3)*16;
      s16x8 v0, v1;
      #pragma unroll
      for (int e=0;e<8;++e){ v0[e] = (short)Fs[r][c0b+e]; v1[e] = (short)Fs[r][c0b+8+e]; }
      *(s16x8*)(fb + (size_t)(i0+r)*HD + c0b)     = v0;
      *(s16x8*)(fb + (size_t)(i0+r)*HD + c0b + 8) = v1;
    }
    {
      int h = t>>2, n1 = (t&3)*16;
      s16x8 w0, w1;
      #pragma unroll
      for (int e=0;e<8;++e){ w0[e] = (short)Fs[n1+e][h]; w1[e] = (short)Fs[n1+8+e][h]; }
      *(s16x8*)(fbT + (size_t)h*NN + i0 + n1)     = w0;
      *(s16x8*)(fbT + (size_t)h*NN + i0 + n1 + 8) = w1;
    }
  }
}

// ---- 2. ecT partials: ecT4[z>>2][e][c] += ... -- bf16 MFMA, 4-way atomic contention. ----
__global__ void __launch_bounds__(256, 2)
k_ect_mfma(const unsigned short* __restrict__ fT, const unsigned short* __restrict__ aT,
           float* __restrict__ ecT4){
  __shared__ __align__(16) unsigned char sm[65536];
  const int t = threadIdx.x, lane = t & 63, w = t >> 6;
  const int wr = w >> 1, wc = w & 1;
  const int m0 = blockIdx.x*128, n0 = blockIdx.y*128, kb = blockIdx.z*256;
  const unsigned short* PA = fT + (size_t)m0*NN + kb;
  const unsigned short* PB = aT + (size_t)n0*NN + kb;
  float* ep = ecT4 + (size_t)(blockIdx.z>>2)*NE*DIN;
  f32x4 acc[4][4] = {};
  STAGE128(sm, PA, NN, PB, NN, 0);
  __syncthreads();
  int cur = 0;
  for (int kt = 0; kt < 4; ++kt){
    if (kt < 3) STAGE128(sm + (cur^1)*32768, PA, NN, PB, NN, (kt+1)*64);
    COMPUTE64(sm + cur*32768);
    __syncthreads();
    cur ^= 1;
  }
  #pragma unroll
  for (int mi = 0; mi < 4; ++mi)
    #pragma unroll
    for (int q = 0; q < 4; ++q){
      int c = m0 + wr*64 + mi*16 + (lane>>4)*4 + q;
      #pragma unroll
      for (int ni = 0; ni < 4; ++ni){
        int e = n0 + wc*64 + ni*16 + (lane & 15);
        atomicAdd(&ep[(size_t)e*DIN + c], acc[mi][ni][q]);
      }
    }
}

// ---- 5+6 fused MFMA attention. dpre -> 8 partial buffers (2-way atomics). ----
#define STAGE_ATTN(buf, j0s) do{ \
  _Pragma("unroll") \
  for (int p_=0;p_<2;++p_){ \
    int r_  = p_*32 + (t>>3); \
    int cs_ = ((t&7) ^ (r_&7))*8; \
    __builtin_amdgcn_global_load_lds( \
      (const __attribute__((address_space(1))) void*)(fb + (size_t)((j0s)+r_)*HD + cs_), \
      (__attribute__((address_space(3))) void*)(sm + (buf)*16384 + p_*4096 + t*16), 16, 0, 0); \
    __builtin_amdgcn_global_load_lds( \
      (const __attribute__((address_space(1))) void*)(fbT + (size_t)r_*NN + (j0s) + cs_), \
      (__attribute__((address_space(3))) void*)(sm + (buf)*16384 + 8192 + p_*4096 + t*16), 16, 0, 0); \
  } }while(0)

__global__ void __launch_bounds__(256)
k_attn(const unsigned short* __restrict__ fb, const unsigned short* __restrict__ fbT,
       float* __restrict__ dpre_p, float* __restrict__ rowsum){
  __shared__ __align__(16) unsigned char sm[49152];
  const int t  = threadIdx.x;
  const int l  = t & 63;
  const int w  = t >> 6;
  const int g  = l >> 4;
  const int i0 = blockIdx.x*64;
  const int jb0 = blockIdx.y*256;
  float* dp = dpre_p + (size_t)(blockIdx.y & 7)*NN*HD;

  s16x8 aQ[2];
  {
    const unsigned short* src = fb + (size_t)(i0 + w*16 + (l&15))*HD + g*8;
    aQ[0] = *(const s16x8*)(src);
    aQ[1] = *(const s16x8*)(src + 32);
  }

  f32x4 acco[4];
  #pragma unroll
  for (int nh=0;nh<4;++nh)
    #pragma unroll
    for (int q=0;q<4;++q) acco[nh][q] = 0.f;
  float rsum[4] = {0.f,0.f,0.f,0.f};

  float* Pw = (float*)(sm + 32768 + w*4096);   // wave-private [16][64] f32, swizzled

  STAGE_ATTN(0, jb0);
  __syncthreads();
  int cur = 0;
  for (int jt = 0; jt < 4; ++jt){
    if (jt < 3) STAGE_ATTN(cur^1, jb0 + (jt+1)*64);
    const unsigned char* B = sm + cur*16384;

    f32x4 accs[4];
    #pragma unroll
    for (int nj=0;nj<4;++nj)
      #pragma unroll
      for (int q=0;q<4;++q) accs[nj][q] = 0.f;
    #pragma unroll
    for (int kk=0; kk<2; ++kk){
      int s = kk*4 + g;
      #pragma unroll
      for (int nj=0;nj<4;++nj){
        int row = nj*16 + (l&15);
        s16x8 b = *(const s16x8*)(B + row*128 + ((s ^ (row&7))*16));
        accs[nj] = __builtin_amdgcn_mfma_f32_16x16x32_bf16(aQ[kk], b, accs[nj], 0,0,0);
      }
    }

    #pragma unroll
    for (int q=0;q<4;++q){
      int i  = g*4 + q;
      int sw = (i&7)<<2;
      #pragma unroll
      for (int nj=0;nj<4;++nj){
        float p = __expf(accs[nj][q]*0.125f);
        rsum[q] += p;
        Pw[i*64 + ((nj*16 + (l&15)) ^ sw)] = p;
      }
    }

    #pragma unroll
    for (int kk=0; kk<2; ++kk){
      int i  = l & 15;
      int sw = (i&7)<<2;
      int jb = g*8 + kk*32;
      f32x4 va = *(const f32x4*)(Pw + i*64 + ( jb      ^ sw));
      f32x4 vb = *(const f32x4*)(Pw + i*64 + ((jb + 4) ^ sw));
      s16x8 pa;
      #pragma unroll
      for (int e=0;e<4;++e){
        float fa = va[e], fbv = vb[e];
        pa[e]   = (short)f2b_rne(fa);
        pa[4+e] = (short)f2b_rne(fbv);
      }
      int s = kk*4 + g;
      #pragma unroll
      for (int nh=0;nh<4;++nh){
        int row = nh*16 + (l&15);
        s16x8 bT = *(const s16x8*)(B + 8192 + row*128 + ((s ^ (row&7))*16));
        acco[nh] = __builtin_amdgcn_mfma_f32_16x16x32_bf16(pa, bT, acco[nh], 0,0,0);
      }
    }
    __syncthreads();
    cur ^= 1;
  }

  #pragma unroll
  for (int q=0;q<4;++q){
    float v = rsum[q];
    v += __shfl_xor(v,1); v += __shfl_xor(v,2);
    v += __shfl_xor(v,4); v += __shfl_xor(v,8);
    if ((l&15)==0) atomicAdd(&rowsum[i0 + w*16 + g*4 + q], v);
  }
  #pragma unroll
  for (int nh=0;nh<4;++nh)
    #pragma unroll
    for (int q=0;q<4;++q)
      atomicAdd(&dp[(size_t)(i0 + w*16 + g*4 + q)*HD + nh*16 + (l&15)], acco[nh][q]);
}

// ---- 3+7 fused k_sd: blocks [0,256) = LN1 path (lin_w staged in LDS, 4 ecT partials);
//      blocks [256,1280) = LN2 path (sums 8 dpre partials). ----
__global__ void __launch_bounds__(256)
k_sd(const float* __restrict__ ecT4, const float* __restrict__ colsum,
     const float* __restrict__ lin_w,
     const float* __restrict__ ln1w, const float* __restrict__ ln1b,
     const float* __restrict__ wow,
     unsigned short* __restrict__ swb, float* __restrict__ sq_s,
     const float* __restrict__ dpre_p, const float* __restrict__ rowsum,
     const float* __restrict__ ln2w, const float* __restrict__ ln2b,
     unsigned short* __restrict__ dmatb, float* __restrict__ sq_d){
  __shared__ float Lw[64][257];   // (h + c) % 32 banks -> 2-way only
  const int b = blockIdx.x, t = threadIdx.x;
  if (b < 256){
    for (int idx = t; idx < 64*DIN; idx += 256) Lw[idx>>8][idx&255] = lin_w[idx];
    __syncthreads();
    int w = t>>6, h = t&63;
    int e = b*4 + w;
    const float* r0 = ecT4 + (size_t)e*DIN;
    float acc = 0.f;
    #pragma unroll 4
    for (int c = 0; c < DIN; ++c){
      float rv = r0[c] + r0[(size_t)NE*DIN + c]
               + r0[2*(size_t)NE*DIN + c] + r0[3*(size_t)NE*DIN + c];
      acc += rv * Lw[h][c];
    }
    acc /= colsum[e];
    float tot = acc;
    for (int m=32;m>=1;m>>=1) tot += __shfl_xor(tot,m);
    float mean = tot*(1.f/64.f);
    float dv = acc - mean;
    float vv = dv*dv;
    for (int m=32;m>=1;m>>=1) vv += __shfl_xor(vv,m);
    float y = dv*(1.f/sqrtf(vv*(1.f/64.f)+1e-5f))*ln1w[h] + ln1b[h];
    float wv = wow[h];
    swb[(size_t)e*HD + h] = f2b_rne(y*wv);
    float q = wv*y*y;
    for (int m=32;m>=1;m>>=1) q += __shfl_xor(q,m);
    if (h==0) sq_s[e] = q;
  } else {
    int lane = t & 63;
    int n = (b-256)*4 + (t>>6);
    float x = 0.f;
    #pragma unroll
    for (int p = 0; p < 8; ++p) x += dpre_p[(size_t)p*NN*HD + (size_t)n*HD + lane];
    x /= rowsum[n];
    float tot = x;
    for (int m=32;m>=1;m>>=1) tot += __shfl_xor(tot,m);
    float mean = tot*(1.f/64.f);
    float dv = x - mean;
    float vv = dv*dv;
    for (int m=32;m>=1;m>>=1) vv += __shfl_xor(vv,m);
    float y = dv*(1.f/sqrtf(vv*(1.f/64.f)+1e-5f))*ln2w[lane] + ln2b[lane];
    dmatb[(size_t)n*HD + lane] = f2b_rne(y);
    float wv = wow[lane];
    float q = wv*y*y;
    for (int m=32;m>=1;m>>=1) q += __shfl_xor(q,m);
    if (lane==0) sq_d[n] = q;
  }
}

// ---- 8. Hm + DE/DV partials -- MFMA (unchanged). ----
__global__ void __launch_bounds__(256)
k_hm(const unsigned short* __restrict__ dmatb, const unsigned short* __restrict__ swb,
     const float* __restrict__ sq_d, const float* __restrict__ sq_s,
     const float* __restrict__ wob, bf16* __restrict__ Hm,
     float* __restrict__ DE, float* __restrict__ DVacc){
  __shared__ __align__(16) unsigned char sm[8192];
  __shared__ float DEp[64];
  const int t = threadIdx.x, l = t & 63, w = t >> 6, g = l >> 4;
  const int n0 = blockIdx.x*64, e0 = blockIdx.y*64;
  #pragma unroll
  for (int p = 0; p < 2; ++p){
    int r  = p*32 + (t>>3);
    int cs = ((t&7) ^ (r&7))*8;
    __builtin_amdgcn_global_load_lds(
      (const __attribute__((address_space(1))) void*)(swb + (size_t)(e0+r)*HD + cs),
      (__attribute__((address_space(3))) void*)(sm + p*4096 + t*16), 16, 0, 0);
  }
  s16x8 aQ[2];
  {
    const unsigned short* src = dmatb + (size_t)(n0 + w*16 + (l&15))*HD + g*8;
    aQ[0] = *(const s16x8*)(src);
    aQ[1] = *(const s16x8*)(src + 32);
  }
  if (t < 64) DEp[t] = 0.f;
  f32x4 accs[4];
  #pragma unroll
  for (int nj=0;nj<4;++nj)
    #pragma unroll
    for (int q=0;q<4;++q) accs[nj][q] = 0.f;
  __syncthreads();
  #pragma unroll
  for (int kk=0; kk<2; ++kk){
    int s = kk*4 + g;
    #pragma unroll
    for (int nj=0;nj<4;++nj){
      int row = nj*16 + (l&15);
      s16x8 b = *(const s16x8*)(sm + row*128 + ((s ^ (row&7))*16));
      accs[nj] = __builtin_amdgcn_mfma_f32_16x16x32_bf16(aQ[kk], b, accs[nj], 0,0,0);
    }
  }
  float bias = wob[0];
  float sqd[4];
  #pragma unroll
  for (int q=0;q<4;++q) sqd[q] = sq_d[n0 + w*16 + g*4 + q];
  float rowp[4] = {0.f,0.f,0.f,0.f};
  #pragma unroll
  for (int nj=0;nj<4;++nj){
    int e = e0 + nj*16 + (l&15);
    float sqs = sq_s[e];
    float colp = 0.f;
    #pragma unroll
    for (int q=0;q<4;++q){
      float ta = sqs + sqd[q] - 2.f*accs[nj][q] + bias;
      float arg = -ta*(1.f/800.f);
      if (!(arg > -88.f)) arg = -88.f;
      if (arg > 60.f)     arg = 60.f;
      int n = n0 + w*16 + g*4 + q;
      bf16 hv = __float2bfloat16(__expf(arg));
      Hm[(size_t)n*NE + e] = hv;
      float vr = b2f(hv);
      rowp[q] += vr;
      colp    += vr;
    }
    atomicAdd(&DEp[nj*16 + (l&15)], colp);
  }
  #pragma unroll
  for (int q=0;q<4;++q){
    float v = rowp[q];
    v += __shfl_xor(v,1); v += __shfl_xor(v,2);
    v += __shfl_xor(v,4); v += __shfl_xor(v,8);
    if ((l&15)==0) atomicAdd(&DVacc[n0 + w*16 + g*4 + q], v);
  }
  __syncthreads();
  if (t < 64) atomicAdd(&DE[e0 + t], DEp[t]);
}

// ---- 10b. In-place: A2[n][e] = Hm[n][e] * rsqrt(DE[e]) (unchanged) ----
__global__ void k_scale(bf16* __restrict__ Hm, const float* __restrict__ DE){
  int idx = blockIdx.x*256 + threadIdx.x;
  int row = idx >> 7, c8 = idx & 127;
  size_t base = (size_t)row*NE + c8*8;
  s16x8 v = *(const s16x8*)(Hm + base);
  s16x8 o;
  #pragma unroll
  for (int j = 0; j < 8; ++j){
    float de = DE[c8*8 + j];
    float r  = (de > 0.f) ? rsqrtf(de) : 0.f;
    unsigned int ww = ((unsigned int)(unsigned short)v[j]) << 16;
    float fv; __builtin_memcpy(&fv, &ww, 4);
    fv *= r;
    o[j] = (short)f2b_rne(fv);
  }
  *(s16x8*)(Hm + base) = o;
}

// ---- 11. k_final (unchanged from R5). ----
__global__ void __launch_bounds__(256, 2)
k_final(const bf16* __restrict__ A2, const float* __restrict__ DVacc,
        const float* __restrict__ G, float* __restrict__ out){
  __shared__ __align__(16) unsigned char sm[128*132*4];
  const int t    = threadIdx.x;
  const int lane = t & 63;
  const int w    = t >> 6;
  const int wr   = w >> 1, wc = w & 1;

  int bid = blockIdx.x;
  int idx = (bid & 7)*66 + (bid >> 3);
  int bi = (int)(32.5f - sqrtf(32.5f*32.5f - 2.f*(float)idx));
  while ((bi+1)*32 - ((bi+1)*bi)/2 <= idx) ++bi;
  while (bi*32 - (bi*(bi-1))/2 > idx) --bi;
  int bj = bi + (idx - (bi*32 - (bi*(bi-1))/2));
  const int i0 = bi*128, j0 = bj*128;

  const bf16* PA = A2 + (size_t)i0*NE;
  const bf16* PB = A2 + (size_t)j0*NE;

  f32x4 acc[4][4] = {};
  STAGE128(sm, PA, NE, PB, NE, 0);
  __syncthreads();
  int cur = 0;
  for (int kt = 0; kt < 16; ++kt){
    if (kt < 15) STAGE128(sm + (cur^1)*32768, PA, NE, PB, NE, (kt+1)*64);
    COMPUTE64(sm + cur*32768);
    __syncthreads();
    cur ^= 1;
  }

  float dvi[4][4], dvj[4];
  #pragma unroll
  for (int mi = 0; mi < 4; ++mi)
    #pragma unroll
    for (int q = 0; q < 4; ++q){
      float v = DVacc[i0 + wr*64 + mi*16 + (lane>>4)*4 + q];
      dvi[mi][q] = (v > 0.f) ? rsqrtf(v) : 0.f;
    }
  #pragma unroll
  for (int ni = 0; ni < 4; ++ni){
    float v = DVacc[j0 + wc*64 + ni*16 + (lane & 15)];
    dvj[ni] = (v > 0.f) ? rsqrtf(v) : 0.f;
  }

  float (*T)[132] = (float(*)[132])sm;
  #pragma unroll
  for (int mi = 0; mi < 4; ++mi)
    #pragma unroll
    for (int ni = 0; ni < 4; ++ni)
      #pragma unroll
      for (int q = 0; q < 4; ++q)
        T[wr*64 + mi*16 + (lane>>4)*4 + q][wc*64 + ni*16 + (lane & 15)] =
          0.01f*(dvi[mi][q]*dvj[ni]*acc[mi][ni][q]);
  __syncthreads();

  #pragma unroll
  for (int it = 0; it < 16; ++it){
    int idx2 = it*256 + t;
    int il = idx2 >> 5;
    int jc = (idx2 & 31)*4;
    size_t o = (size_t)(i0+il)*NN + j0 + jc;
    float4 gv = *(const float4*)(G + o);
    float4 r;
    r.x = 0.99f*gv.x + T[il][jc+0];
    r.y = 0.99f*gv.y + T[il][jc+1];
    r.z = 0.99f*gv.z + T[il][jc+2];
    r.w = 0.99f*gv.w + T[il][jc+3];
    *(float4*)(out + o) = r;
  }

  if (bi == bj) return;
  __syncthreads();
  #pragma unroll
  for (int mi = 0; mi < 4; ++mi)
    #pragma unroll
    for (int ni = 0; ni < 4; ++ni)
      #pragma unroll
      for (int q = 0; q < 4; ++q)
        T[wc*64 + ni*16 + (lane & 15)][wr*64 + mi*16 + (lane>>4)*4 + q] =
          0.01f*(dvi[mi][q]*dvj[ni]*acc[mi][ni][q]);
  __syncthreads();
  #pragma unroll
  for (int it = 0; it < 16; ++it){
    int idx2 = it*256 + t;
    int jl = idx2 >> 5;
    int ic = (idx2 & 31)*4;
    size_t o = (size_t)(j0+jl)*NN + i0 + ic;
    float4 gv = *(const float4*)(G + o);
    float4 r;
    r.x = 0.99f*gv.x + T[jl][ic+0];
    r.y = 0.99f*gv.y + T[jl][ic+1];
    r.z = 0.99f*gv.z + T[jl][ic+2];
    r.w = 0.99f*gv.w + T[jl][ic+3];
    *(float4*)(out + o) = r;
  }
}

extern "C" void kernel_launch(void* const* d_in, const int* in_sizes, int n_in,
                              void* d_out, int out_size, void* d_ws, size_t ws_size,
                              hipStream_t stream){
  const float* adj  = (const float*)d_in[0];
  const float* G    = (const float*)d_in[1];
  const float* feats= (const float*)d_in[2];
  const float* Wv   = (const float*)d_in[3];
  const float* lin  = (const float*)d_in[4];
  const float* wow  = (const float*)d_in[5];
  const float* wob  = (const float*)d_in[6];
  const float* ln1w = (const float*)d_in[7];
  const float* ln1b = (const float*)d_in[8];
  const float* ln2w = (const float*)d_in[9];
  const float* ln2b = (const float*)d_in[10];
  float* out = (float*)d_out;

  float* w = (float*)d_ws;
  float* colsum = w; w += NE;
  float* DE     = w; w += NE;
  float* sq_s   = w; w += NE;
  float* rowsum = w; w += NN;
  float* sq_d   = w; w += NN;
  float* DVacc  = w; w += NN;
  float* ecT4   = w; w += 4*(size_t)NE*DIN;                   // 4 partial buffers, 4 MB
  unsigned short* swb    = (unsigned short*)w; w += NE*HD/2;  // bf16 s*w_o
  unsigned short* dmatb  = (unsigned short*)w; w += NN*HD/2;  // bf16 d
  unsigned short* fbm    = (unsigned short*)w; w += NN*HD/2;  // bf16 f
  unsigned short* fbT    = (unsigned short*)w; w += NN*HD/2;  // bf16 f^T
  unsigned short* featsT = (unsigned short*)w; w += NN*DIN/2; // bf16 feats^T
  bf16*  Hm     = (bf16*)w;     // 8 MB
  unsigned short* adjT = (unsigned short*)Hm;  // aliases Hm: dead after k_ect_mfma
  float* dpre_p = (float*)Hm;   // 8 x 1MB partials, aliases Hm: written after k_ect
                                // (memset below is stream-ordered after k_ect), consumed
                                // by k_sd before k_hm overwrites Hm.

  hipMemsetAsync(colsum, 0, NE*sizeof(float), stream);
  hipMemsetAsync(DE,     0, NE*sizeof(float), stream);
  hipMemsetAsync(rowsum, 0, NN*sizeof(float), stream);
  hipMemsetAsync(DVacc,  0, NN*sizeof(float), stream);
  hipMemsetAsync(ecT4,   0, 4*(size_t)NE*DIN*sizeof(float), stream);

  k_prep    <<<1344,         256, 0, stream>>>(feats, adj, Wv, featsT, adjT, colsum, fbm, fbT);
  k_ect_mfma<<<dim3(2,8,16), 256, 0, stream>>>(featsT, adjT, ecT4);
  hipMemsetAsync(dpre_p, 0, 8*(size_t)NN*HD*sizeof(float), stream);   // after k_ect (adjT dead)
  k_attn    <<<dim3(64,16),  256, 0, stream>>>(fbm, fbT, dpre_p, rowsum);
  k_sd      <<<1280,         256, 0, stream>>>(ecT4, colsum, lin, ln1w, ln1b, wow, swb, sq_s,
                                               dpre_p, rowsum, ln2w, ln2b, dmatb, sq_d);
  k_hm      <<<dim3(64,16),  256, 0, stream>>>(dmatb, swb, sq_d, sq_s, wob, Hm, DE, DVacc);
  k_scale   <<<2048,         256, 0, stream>>>(Hm, DE);
  k_final   <<<528,          256, 0, stream>>>(Hm, DVacc, G, out);
}